// Round 1
// 4468.094 us; speedup vs baseline: 1.4261x; 1.4261x over previous
//
#include <hip/hip_runtime.h>
#include <stdint.h>

// Problem constants (fixed by reference): B=32, T=512, d=1024, Kcb=256
#define NB    32
#define NT    512
#define ND    1024
#define NG    3072      // 3*d
#define NROW  16384     // B*T
#define KCB   256
#define GRU_BLOCKS 128

typedef float  f32x4 __attribute__((ext_vector_type(4)));
typedef short  s16x8 __attribute__((ext_vector_type(8)));

// ---------------- bf16 helpers (hi/lo split precision) ----------------
__device__ __forceinline__ unsigned short f32_to_bf16(float x) {
    union { float f; unsigned int u; } v; v.f = x;
    unsigned int u = v.u;
    return (unsigned short)((u + 0x7FFFu + ((u >> 16) & 1u)) >> 16);
}
__device__ __forceinline__ float bf16_to_f32(unsigned short h) {
    union { float f; unsigned int u; } v; v.u = ((unsigned int)h) << 16; return v.f;
}

// LLC-coherent (L1/L2-bypassing) 16B load / 2B store — cross-XCD fresh without fences.
__device__ __forceinline__ s16x8 llc_load16(const unsigned short* p) {
    s16x8 r;
    asm volatile("global_load_dwordx4 %0, %1, off sc0 sc1" : "=v"(r) : "v"(p) : "memory");
    return r;
}
__device__ __forceinline__ void llc_store2(unsigned short* p, unsigned int v) {
    asm volatile("global_store_short %0, %1, off sc0 sc1" :: "v"(p), "v"(v) : "memory");
}
// Relaxed LLC-level 4B store: publishes the step slot WITHOUT the agent-release
// buffer_wbl2 (full L2 dirty writeback + drain) that __hip_atomic_store(RELEASE,
// AGENT) emits. Ordering vs the hA data is already guaranteed: hA is written with
// sc0|sc1 write-through stores drained by s_waitcnt vmcnt(0) before this store.
__device__ __forceinline__ void llc_store4(int* p, int v) {
    asm volatile("global_store_dword %0, %1, off sc0 sc1" :: "v"(p), "v"(v) : "memory");
}

// ---------------- W_hh -> bf16 hi/lo split (once per launch) ----------------
__global__ __launch_bounds__(256) void prep_w(const float* __restrict__ W,
                                              unsigned short* __restrict__ Whi,
                                              unsigned short* __restrict__ Wlo) {
    int i = blockIdx.x * 256 + threadIdx.x;   // grid sized exactly: 3072*1024/256
    float w = W[i];
    unsigned short hi = f32_to_bf16(w);
    float rem = w - bf16_to_f32(hi);
    Whi[i] = hi;
    Wlo[i] = f32_to_bf16(rem);
}

// ---------------- quantize: fp64 scores, argmin, copy row, SSD ----------------
__global__ __launch_bounds__(256) void quantize_kernel(
    const float* __restrict__ feat, const float* __restrict__ cb,
    float* __restrict__ out_q, float* __restrict__ out_idx,
    int* __restrict__ idxi, float* __restrict__ acc)
{
    __shared__ float  fr[8][1024];     // 32 KB
    __shared__ double wsco[4];
    __shared__ int    wid[4];
    __shared__ int    winner;
    __shared__ float  sp[4];

    int tid = threadIdx.x;
    int r0  = blockIdx.x * 8;

    for (int i = 0; i < 8; ++i) {
        int g   = i * 256 + tid;
        int row = g >> 8;
        int kq  = g & 255;
        float4 v = ((const float4*)(feat + (long)(r0 + row) * ND))[kq];
        ((float4*)&fr[row][0])[kq] = v;
    }
    __syncthreads();

    double dot[8];
    #pragma unroll
    for (int r = 0; r < 8; ++r) dot[r] = 0.0;
    double cc = 0.0;
    const float4* cbrow = (const float4*)(cb + (long)tid * ND);
    for (int k4 = 0; k4 < 256; ++k4) {
        float4 c = cbrow[k4];
        cc += (double)c.x * (double)c.x + (double)c.y * (double)c.y
            + (double)c.z * (double)c.z + (double)c.w * (double)c.w;
        #pragma unroll
        for (int r = 0; r < 8; ++r) {
            float4 f = ((const float4*)&fr[r][0])[k4];
            dot[r] += (double)(f.x * c.x) + (double)(f.y * c.y)
                    + (double)(f.z * c.z) + (double)(f.w * c.w);
        }
    }

    float ssd_thread = 0.f;
    for (int r = 0; r < 8; ++r) {
        double s = cc - 2.0 * dot[r];
        int idx = tid;
        #pragma unroll
        for (int m = 1; m < 64; m <<= 1) {
            double s2 = __shfl_xor(s, m, 64);
            int    i2 = __shfl_xor(idx, m, 64);
            if (s2 < s || (s2 == s && i2 < idx)) { s = s2; idx = i2; }
        }
        int w = tid >> 6;
        if ((tid & 63) == 0) { wsco[w] = s; wid[w] = idx; }
        __syncthreads();
        if (tid == 0) {
            double bs = wsco[0]; int bi = wid[0];
            for (int w2 = 1; w2 < 4; ++w2)
                if (wsco[w2] < bs || (wsco[w2] == bs && wid[w2] < bi)) { bs = wsco[w2]; bi = wid[w2]; }
            winner = bi;
            out_idx[r0 + r] = (float)bi;
            idxi[r0 + r]    = bi;
        }
        __syncthreads();
        int win = winner;
        float4 q = ((const float4*)(cb + (long)win * ND))[tid];
        ((float4*)(out_q + (long)(r0 + r) * ND))[tid] = q;
        float4 f = ((const float4*)&fr[r][0])[tid];
        float dx = f.x - q.x, dy = f.y - q.y, dz = f.z - q.z, dw = f.w - q.w;
        ssd_thread += dx * dx + dy * dy + dz * dz + dw * dw;
        __syncthreads();
    }

    #pragma unroll
    for (int m = 1; m < 64; m <<= 1) ssd_thread += __shfl_xor(ssd_thread, m, 64);
    if ((tid & 63) == 0) sp[tid >> 6] = ssd_thread;
    __syncthreads();
    if (tid == 0) atomicAdd(&acc[33], sp[0] + sp[1] + sp[2] + sp[3]);
}

// ---------------- fp32 tiled GEMM: C[M,N] = A[M,K] * W[N,K]^T + bias[N] ----------------
__global__ __launch_bounds__(256) void gemm_nt(
    const float* __restrict__ A, const float* __restrict__ W,
    const float* __restrict__ bias, float* __restrict__ C, int N, int K)
{
    __shared__ float As[16][132];
    __shared__ float Bs[16][132];
    int tid = threadIdx.x;
    int m0 = blockIdx.y * 128;
    int n0 = blockIdx.x * 128;
    int tx = tid & 15, ty = tid >> 4;

    float accum[8][8];
    #pragma unroll
    for (int i = 0; i < 8; ++i)
        #pragma unroll
        for (int j = 0; j < 8; ++j) accum[i][j] = 0.f;

    for (int k0 = 0; k0 < K; k0 += 16) {
        #pragma unroll
        for (int i = 0; i < 2; ++i) {
            int f   = tid + i * 256;
            int row = f >> 2;
            int kq  = f & 3;
            float4 a = *(const float4*)(A + (long)(m0 + row) * K + k0 + kq * 4);
            As[kq * 4 + 0][row] = a.x; As[kq * 4 + 1][row] = a.y;
            As[kq * 4 + 2][row] = a.z; As[kq * 4 + 3][row] = a.w;
            float4 b = *(const float4*)(W + (long)(n0 + row) * K + k0 + kq * 4);
            Bs[kq * 4 + 0][row] = b.x; Bs[kq * 4 + 1][row] = b.y;
            Bs[kq * 4 + 2][row] = b.z; Bs[kq * 4 + 3][row] = b.w;
        }
        __syncthreads();
        #pragma unroll
        for (int kk = 0; kk < 16; ++kk) {
            float4 a01 = *(const float4*)&As[kk][ty * 8];
            float4 a23 = *(const float4*)&As[kk][ty * 8 + 4];
            float4 b01 = *(const float4*)&Bs[kk][tx * 8];
            float4 b23 = *(const float4*)&Bs[kk][tx * 8 + 4];
            float av[8] = {a01.x, a01.y, a01.z, a01.w, a23.x, a23.y, a23.z, a23.w};
            float bv[8] = {b01.x, b01.y, b01.z, b01.w, b23.x, b23.y, b23.z, b23.w};
            #pragma unroll
            for (int i = 0; i < 8; ++i)
                #pragma unroll
                for (int j = 0; j < 8; ++j) accum[i][j] += av[i] * bv[j];
        }
        __syncthreads();
    }
    #pragma unroll
    for (int i = 0; i < 8; ++i) {
        float* crow = C + (long)(m0 + ty * 8 + i) * N + n0 + tx * 8;
        const float* brow = bias + n0 + tx * 8;
        float4 o0, o1;
        o0.x = accum[i][0] + brow[0]; o0.y = accum[i][1] + brow[1];
        o0.z = accum[i][2] + brow[2]; o0.w = accum[i][3] + brow[3];
        o1.x = accum[i][4] + brow[4]; o1.y = accum[i][5] + brow[5];
        o1.z = accum[i][6] + brow[6]; o1.w = accum[i][7] + brow[7];
        *(float4*)(crow)     = o0;
        *(float4*)(crow + 4) = o1;
    }
}

// ---------------- persistent GRU v5: relaxed slot publish (no wbl2) ----------------
// 128 blocks x 256 thr (4 waves), each block owns 8 j-cols.
// W-hi pinned in LDS, W-lo pinned in regs. h handed between steps as bf16 hi/lo
// ushorts in A-fragment layout via sc0|sc1 (LLC-coherent) accesses: 16B vector
// loads, ALL 32 issued before a single waitcnt -> one LLC latency per step.
// Barrier: per-block slot store + all-waves poll (no post-poll syncthreads).
// v5 change: the slot publish is a RELAXED sc0|sc1 store. The previous
// __hip_atomic_store(RELEASE, AGENT) lowered to buffer_wbl2 sc1 + s_waitcnt
// vmcnt(0) + store — a full L2 dirty-line writeback waited-for on every step's
// critical path (before a global barrier, so the slowest block's wbl2 taxed all).
// The hA data the pollers consume is already at the LLC before this store: it is
// written with sc0|sc1 write-through stores and drained by s_waitcnt vmcnt(0)
// before __syncthreads().
__global__ __launch_bounds__(256, 1) void gru_persist(
    float* hs,
    const unsigned short* __restrict__ Whi, const unsigned short* __restrict__ Wlo,
    const float* __restrict__ GIcb, const int* __restrict__ idxi,
    const float* __restrict__ b_hh,
    unsigned short* hA,   // [2 buf][hi/lo][32 kk][2 mt][64 lane][8] ushorts (64KB/part)
    int* slots)           // [128] per-block completed-step epochs
{
    __shared__ unsigned short whi[3][32][8][32];   // 48 KB: W-hi in B-frag layout
    __shared__ float red[4][32][25];               // 12.8 KB: k-split partials

    int tid  = threadIdx.x;
    int lane = tid & 63;
    int w    = tid >> 6;
    int bid  = blockIdx.x;
    int jb   = bid * 8;
    int q    = lane >> 4;
    int n7   = lane & 7;

    // ---- stage W-hi slice into LDS, once (24 rows x 1024 = 3072 ushort8 -> 12 iters) ----
    for (int it = 0; it < 12; ++it) {
        int u8 = it * 256 + tid;
        int e  = u8 * 8;
        int r24 = e >> 10;
        int k   = e & 1023;
        int g = r24 >> 3, r = r24 & 7;
        s16x8 v = *(const s16x8*)(Whi + (long)((g << 10) + jb + r) * 1024 + k);
        *(s16x8*)&whi[g][k >> 5][r][k & 31] = v;
    }

    // ---- pin W-lo fragments in registers (wave w covers k in [w*256, w*256+256)) ----
    s16x8 wlof[8][3];
    #pragma unroll
    for (int kl = 0; kl < 8; ++kl)
        #pragma unroll
        for (int g = 0; g < 3; ++g) {
            int kg = w * 256 + kl * 32 + q * 8;
            wlof[kl][g] = *(const s16x8*)(Wlo + (long)((g << 10) + jb + n7) * 1024 + kg);
        }
    __syncthreads();

    // ---- epilogue constants: thread -> one output (b=eb, col jg) ----
    int eb  = tid >> 3;                    // batch 0..31
    int ejl = tid & 7;                     // j-local 0..7
    int jg  = jb + ejl;
    int emt = eb >> 4, erow = eb & 15;
    int eq  = erow >> 2, eer = erow & 3;
    int esidx = eq * 8 + ejl;
    float bhr = b_hh[jg], bhz = b_hh[ND + jg], bhn = b_hh[2 * ND + jg];
    // hA write slot (A-frag layout): kk=jg>>5, q'=(jg>>3)&3, e=jg&7, lane'=q'*16+(eb&15)
    int akk = jg >> 5, aqp = (jg >> 3) & 3, aj8 = jg & 7;
    int alane = aqp * 16 + (eb & 15);
    int awoff = ((akk * 2 + emt) * 64 + alane) * 8 + aj8;
    float hp = 0.f;                        // h_prev carried in-register

    #pragma unroll 1
    for (int t = 0; t < NT; ++t) {
        // prefetch gate inputs (barrier-independent, cached reads)
        int cidx = idxi[eb * NT + t];
        const float* gib = GIcb + (long)cidx * NG;
        float gi0 = gib[jg], gi1 = gib[ND + jg], gi2 = gib[2 * ND + jg];

        // all waves poll: all 128 blocks completed step t-1 (slot >= t)
        if (t > 0) {
            bool ok;
            do {
                int s1 = __hip_atomic_load(slots + lane,      __ATOMIC_RELAXED, __HIP_MEMORY_SCOPE_AGENT);
                int s2 = __hip_atomic_load(slots + 64 + lane, __ATOMIC_RELAXED, __HIP_MEMORY_SCOPE_AGENT);
                ok = (__all((s1 >= t) && (s2 >= t)) != 0);
                if (!ok) __builtin_amdgcn_s_sleep(1);
            } while (!ok);
        }

        const unsigned short* rHi = hA + ((unsigned)(t & 1) * 2 + 0) * 32768;
        const unsigned short* rLo = rHi + 32768;
        unsigned short* wHi = hA + ((unsigned)((t + 1) & 1) * 2 + 0) * 32768;
        unsigned short* wLo = wHi + 32768;

        // ---- issue ALL 32 A-fragment loads (16B each), one waitcnt ----
        s16x8 Ah[8][2], Al[8][2];
        #pragma unroll
        for (int kl = 0; kl < 8; ++kl) {
            int kk = w * 8 + kl;
            const unsigned short* ph = rHi + (kk * 2) * 512 + lane * 8;
            const unsigned short* pl = rLo + (kk * 2) * 512 + lane * 8;
            Ah[kl][0] = llc_load16(ph);
            Ah[kl][1] = llc_load16(ph + 512);
            Al[kl][0] = llc_load16(pl);
            Al[kl][1] = llc_load16(pl + 512);
        }
        asm volatile("s_waitcnt vmcnt(0)" ::: "memory");

        f32x4 acc[2][3];
        #pragma unroll
        for (int mt = 0; mt < 2; ++mt)
            #pragma unroll
            for (int g = 0; g < 3; ++g) acc[mt][g] = (f32x4){0.f, 0.f, 0.f, 0.f};

        #pragma unroll
        for (int kl = 0; kl < 8; ++kl) {
            int kk = w * 8 + kl;
            #pragma unroll
            for (int g = 0; g < 3; ++g) {
                s16x8 bh = *(const s16x8*)&whi[g][kk][n7][q * 8];
                s16x8 bl = wlof[kl][g];
                acc[0][g] = __builtin_amdgcn_mfma_f32_16x16x32_bf16(Ah[kl][0], bh, acc[0][g], 0, 0, 0);
                acc[0][g] = __builtin_amdgcn_mfma_f32_16x16x32_bf16(Al[kl][0], bh, acc[0][g], 0, 0, 0);
                acc[0][g] = __builtin_amdgcn_mfma_f32_16x16x32_bf16(Ah[kl][0], bl, acc[0][g], 0, 0, 0);
                acc[1][g] = __builtin_amdgcn_mfma_f32_16x16x32_bf16(Ah[kl][1], bh, acc[1][g], 0, 0, 0);
                acc[1][g] = __builtin_amdgcn_mfma_f32_16x16x32_bf16(Al[kl][1], bh, acc[1][g], 0, 0, 0);
                acc[1][g] = __builtin_amdgcn_mfma_f32_16x16x32_bf16(Ah[kl][1], bl, acc[1][g], 0, 0, 0);
            }
        }

        // k-split partials (only valid j lanes)
        if ((lane & 15) < 8) {
            int sidx = q * 8 + (lane & 15);
            #pragma unroll
            for (int mt = 0; mt < 2; ++mt)
                #pragma unroll
                for (int g = 0; g < 3; ++g)
                    #pragma unroll
                    for (int r = 0; r < 4; ++r)
                        red[w][sidx][(mt * 3 + g) * 4 + r] = acc[mt][g][r];
        }
        __syncthreads();

        // epilogue: 1 output per thread
        float g0 = 0.f, g1 = 0.f, g2 = 0.f;
        #pragma unroll
        for (int ww = 0; ww < 4; ++ww) {
            g0 += red[ww][esidx][(emt * 3 + 0) * 4 + eer];
            g1 += red[ww][esidx][(emt * 3 + 1) * 4 + eer];
            g2 += red[ww][esidx][(emt * 3 + 2) * 4 + eer];
        }
        float xr = gi0 + g0 + bhr;
        float xz = gi1 + g1 + bhz;
        float rg = 1.f / (1.f + __expf(-xr));
        float zg = 1.f / (1.f + __expf(-xz));
        float narg = gi2 + rg * (g2 + bhn);
        float e2 = __expf(2.f * narg);
        float ng = 1.f - 2.f / (e2 + 1.f);
        float hnew = (1.f - zg) * ng + zg * hp;
        hp = hnew;
        hs[((long)eb * NT + t) * ND + jg] = hnew;
        unsigned short hh = f32_to_bf16(hnew);
        unsigned short hl = f32_to_bf16(hnew - bf16_to_f32(hh));
        llc_store2(wHi + awoff, (unsigned int)hh);
        llc_store2(wLo + awoff, (unsigned int)hl);
        asm volatile("s_waitcnt vmcnt(0)" ::: "memory");   // h stores drained to LLC
        __syncthreads();                                   // whole block done
        if (tid == 0)
            llc_store4(slots + bid, t + 1);                // relaxed LLC publish, no wbl2
    }
}

// ---------------- CPC loss: one block per (k,l) ----------------
__global__ __launch_bounds__(256) void cp_kernel(
    const float* __restrict__ feat, const float* __restrict__ ctx,
    const int* __restrict__ perm, float* __restrict__ acc)
{
    __shared__ float cx[32][256];
    __shared__ float red2[4];

    int tid = threadIdx.x;
    int bk = blockIdx.x;
    int kk, l;
    if (bk < 511)       { kk = 1; l = bk; }
    else if (bk < 1021) { kk = 2; l = bk - 511; }
    else                { kk = 3; l = bk - 1021; }

    float dacc[5] = {0.f, 0.f, 0.f, 0.f, 0.f};
    for (int c = 0; c < 4; ++c) {
        for (int i = 0; i < 8; ++i) {
            int g = i * 256 + tid;
            int b = g >> 6, kq = g & 63;
            *(float4*)&cx[b][kq * 4] =
                *(const float4*)(ctx + (long)(b * NT + l) * ND + c * 256 + kq * 4);
        }
        __syncthreads();
        for (int oi = 0; oi < 5; ++oi) {
            int o = tid + oi * 256;
            if (o < 1056) {
                int b = o / 33, ii = o % 33;
                const float* frow = (ii < 32)
                    ? (feat + (long)(perm[(kk - 1) * 32 + ii] * NT + l) * ND)
                    : (feat + (long)(b * NT + l + kk) * ND);
                const float4* fp4 = (const float4*)(frow + c * 256);
                const float4* cp4 = (const float4*)&cx[b][0];
                float s = 0.f;
                for (int k4 = 0; k4 < 64; ++k4) {
                    float4 cf = cp4[k4];
                    float4 ff = fp4[k4];
                    s += cf.x * ff.x + cf.y * ff.y + cf.z * ff.z + cf.w * ff.w;
                }
                dacc[oi] += s;
            }
        }
        __syncthreads();
    }

    float nsum = 0.f;
    for (int oi = 0; oi < 5; ++oi) {
        int o = tid + oi * 256;
        if (o < 1056) {
            int b = o / 33, ii = o % 33;
            float x = dacc[oi];
            if (ii < 32) {
                float sn = 1.f / (1.f + expf(x));
                nsum += -logf(sn + 1e-8f);
            } else {
                float sp = 1.f / (1.f + expf(-x));
                atomicAdd(&acc[b], -logf(sp + 1e-8f));
            }
        }
    }
    #pragma unroll
    for (int m = 1; m < 64; m <<= 1) nsum += __shfl_xor(nsum, m, 64);
    if ((tid & 63) == 0) red2[tid >> 6] = nsum;
    __syncthreads();
    if (tid == 0) atomicAdd(&acc[32], red2[0] + red2[1] + red2[2] + red2[3]);
}

// ---------------- finalize ----------------
__global__ void finalize_kernel(const float* __restrict__ acc, float* __restrict__ out) {
    int b = threadIdx.x;
    if (b < 32) {
        float cp = (acc[b] + 0.25f * acc[32] * (1.0f / 1024.0f)) * (1.0f / 1527.0f);
        float vq = 1.25f * acc[33] * (1.0f / 16777216.0f);
        out[b] = cp + vq;
    }
}

// ---------------- launch ----------------
extern "C" void kernel_launch(void* const* d_in, const int* in_sizes, int n_in,
                              void* d_out, int out_size, void* d_ws, size_t ws_size,
                              hipStream_t stream)
{
    const float* feat   = (const float*)d_in[0];
    const float* cb     = (const float*)d_in[1];
    const float* W_ih   = (const float*)d_in[2];
    const float* W_hh   = (const float*)d_in[3];
    const float* b_ih   = (const float*)d_in[4];
    const float* b_hh   = (const float*)d_in[5];
    const float* W_proj = (const float*)d_in[6];
    const float* b_proj = (const float*)d_in[7];
    const int*   nperm  = (const int*)d_in[8];

    float* outq    = (float*)d_out;
    float* outidx  = outq + 16777216;
    float* outloss = outq + 16793600;

    char* ws = (char*)d_ws;
    float*          hs   = (float*)(ws);                        //  67,108,864 B
    float*          ctx  = (float*)(ws + 67108864);             //  67,108,864 B
    unsigned short* Whi  = (unsigned short*)(ws + 134217728);   //   6,291,456 B
    unsigned short* Wlo  = (unsigned short*)(ws + 140509184);   //   6,291,456 B
    float*          GIcb = (float*)(ws + 146800640);            //   3,145,728 B
    int*            idxi = (int*)(ws + 149946368);              //      65,536 B
    float*          acc  = (float*)(ws + 150011904);            //  256 B acc
    int*            slots= (int*)(ws + 150012160);              //  512 B barrier slots
    unsigned short* hA   = (unsigned short*)(ws + 150012672);   //  262,144 B h frag bufs

    // zero acc (256) + slots (512) + hA buffer 0 hi+lo (131072): one contiguous memset
    hipMemsetAsync(acc, 0, 256 + 512 + 131072, stream);
    prep_w<<<12288, 256, 0, stream>>>(W_hh, Whi, Wlo);
    quantize_kernel<<<2048, 256, 0, stream>>>(feat, cb, outq, outidx, idxi, acc);
    // GIcb = codebook @ W_ih^T + b_ih  (256x3072, K=1024)
    gemm_nt<<<dim3(24, 2), 256, 0, stream>>>(cb, W_ih, b_ih, GIcb, NG, ND);
    // persistent GRU: one launch, 512 in-kernel steps
    gru_persist<<<GRU_BLOCKS, 256, 0, stream>>>(hs, Whi, Wlo, GIcb, idxi, b_hh, hA, slots);
    // context_proj = hs @ W_proj^T + b_proj
    gemm_nt<<<dim3(8, 128), 256, 0, stream>>>(hs, W_proj, b_proj, ctx, ND, ND);
    cp_kernel<<<1530, 256, 0, stream>>>(feat, ctx, nperm, acc);
    finalize_kernel<<<1, 64, 0, stream>>>(acc, outloss);
}

// Round 2
// 3746.124 us; speedup vs baseline: 1.7009x; 1.1927x over previous
//
#include <hip/hip_runtime.h>
#include <stdint.h>

// Problem constants (fixed by reference): B=32, T=512, d=1024, Kcb=256
#define NB    32
#define NT    512
#define ND    1024
#define NG    3072      // 3*d
#define NROW  16384     // B*T
#define KCB   256
#define GRU_BLOCKS 256  // 2 independent batch-groups x 128 col-blocks

typedef float  f32x4 __attribute__((ext_vector_type(4)));
typedef short  s16x8 __attribute__((ext_vector_type(8)));

// ---------------- bf16 helpers (hi/lo split precision) ----------------
__device__ __forceinline__ unsigned short f32_to_bf16(float x) {
    union { float f; unsigned int u; } v; v.f = x;
    unsigned int u = v.u;
    return (unsigned short)((u + 0x7FFFu + ((u >> 16) & 1u)) >> 16);
}
__device__ __forceinline__ float bf16_to_f32(unsigned short h) {
    union { float f; unsigned int u; } v; v.u = ((unsigned int)h) << 16; return v.f;
}

// LLC-coherent (L1/L2-bypassing) 16B load / 2B store — cross-XCD fresh without fences.
__device__ __forceinline__ s16x8 llc_load16(const unsigned short* p) {
    s16x8 r;
    asm volatile("global_load_dwordx4 %0, %1, off sc0 sc1" : "=v"(r) : "v"(p) : "memory");
    return r;
}
__device__ __forceinline__ void llc_store2(unsigned short* p, unsigned int v) {
    asm volatile("global_store_short %0, %1, off sc0 sc1" :: "v"(p), "v"(v) : "memory");
}
// Relaxed LLC-level 4B store: publishes the step slot WITHOUT the agent-release
// buffer_wbl2 (full L2 dirty writeback + drain) that __hip_atomic_store(RELEASE,
// AGENT) emits. Ordering vs the hA data is already guaranteed: hA is written with
// sc0|sc1 write-through stores drained by s_waitcnt vmcnt(0) before this store.
__device__ __forceinline__ void llc_store4(int* p, int v) {
    asm volatile("global_store_dword %0, %1, off sc0 sc1" :: "v"(p), "v"(v) : "memory");
}

// ---------------- W_hh -> bf16 hi/lo split (once per launch) ----------------
__global__ __launch_bounds__(256) void prep_w(const float* __restrict__ W,
                                              unsigned short* __restrict__ Whi,
                                              unsigned short* __restrict__ Wlo) {
    int i = blockIdx.x * 256 + threadIdx.x;   // grid sized exactly: 3072*1024/256
    float w = W[i];
    unsigned short hi = f32_to_bf16(w);
    float rem = w - bf16_to_f32(hi);
    Whi[i] = hi;
    Wlo[i] = f32_to_bf16(rem);
}

// ---------------- quantize: fp64 scores, argmin, copy row, SSD ----------------
__global__ __launch_bounds__(256) void quantize_kernel(
    const float* __restrict__ feat, const float* __restrict__ cb,
    float* __restrict__ out_q, float* __restrict__ out_idx,
    int* __restrict__ idxi, float* __restrict__ acc)
{
    __shared__ float  fr[8][1024];     // 32 KB
    __shared__ double wsco[4];
    __shared__ int    wid[4];
    __shared__ int    winner;
    __shared__ float  sp[4];

    int tid = threadIdx.x;
    int r0  = blockIdx.x * 8;

    for (int i = 0; i < 8; ++i) {
        int g   = i * 256 + tid;
        int row = g >> 8;
        int kq  = g & 255;
        float4 v = ((const float4*)(feat + (long)(r0 + row) * ND))[kq];
        ((float4*)&fr[row][0])[kq] = v;
    }
    __syncthreads();

    double dot[8];
    #pragma unroll
    for (int r = 0; r < 8; ++r) dot[r] = 0.0;
    double cc = 0.0;
    const float4* cbrow = (const float4*)(cb + (long)tid * ND);
    for (int k4 = 0; k4 < 256; ++k4) {
        float4 c = cbrow[k4];
        cc += (double)c.x * (double)c.x + (double)c.y * (double)c.y
            + (double)c.z * (double)c.z + (double)c.w * (double)c.w;
        #pragma unroll
        for (int r = 0; r < 8; ++r) {
            float4 f = ((const float4*)&fr[r][0])[k4];
            dot[r] += (double)(f.x * c.x) + (double)(f.y * c.y)
                    + (double)(f.z * c.z) + (double)(f.w * c.w);
        }
    }

    float ssd_thread = 0.f;
    for (int r = 0; r < 8; ++r) {
        double s = cc - 2.0 * dot[r];
        int idx = tid;
        #pragma unroll
        for (int m = 1; m < 64; m <<= 1) {
            double s2 = __shfl_xor(s, m, 64);
            int    i2 = __shfl_xor(idx, m, 64);
            if (s2 < s || (s2 == s && i2 < idx)) { s = s2; idx = i2; }
        }
        int w = tid >> 6;
        if ((tid & 63) == 0) { wsco[w] = s; wid[w] = idx; }
        __syncthreads();
        if (tid == 0) {
            double bs = wsco[0]; int bi = wid[0];
            for (int w2 = 1; w2 < 4; ++w2)
                if (wsco[w2] < bs || (wsco[w2] == bs && wid[w2] < bi)) { bs = wsco[w2]; bi = wid[w2]; }
            winner = bi;
            out_idx[r0 + r] = (float)bi;
            idxi[r0 + r]    = bi;
        }
        __syncthreads();
        int win = winner;
        float4 q = ((const float4*)(cb + (long)win * ND))[tid];
        ((float4*)(out_q + (long)(r0 + r) * ND))[tid] = q;
        float4 f = ((const float4*)&fr[r][0])[tid];
        float dx = f.x - q.x, dy = f.y - q.y, dz = f.z - q.z, dw = f.w - q.w;
        ssd_thread += dx * dx + dy * dy + dz * dz + dw * dw;
        __syncthreads();
    }

    #pragma unroll
    for (int m = 1; m < 64; m <<= 1) ssd_thread += __shfl_xor(ssd_thread, m, 64);
    if ((tid & 63) == 0) sp[tid >> 6] = ssd_thread;
    __syncthreads();
    if (tid == 0) atomicAdd(&acc[33], sp[0] + sp[1] + sp[2] + sp[3]);
}

// ---------------- fp32 tiled GEMM: C[M,N] = A[M,K] * W[N,K]^T + bias[N] ----------------
__global__ __launch_bounds__(256) void gemm_nt(
    const float* __restrict__ A, const float* __restrict__ W,
    const float* __restrict__ bias, float* __restrict__ C, int N, int K)
{
    __shared__ float As[16][132];
    __shared__ float Bs[16][132];
    int tid = threadIdx.x;
    int m0 = blockIdx.y * 128;
    int n0 = blockIdx.x * 128;
    int tx = tid & 15, ty = tid >> 4;

    float accum[8][8];
    #pragma unroll
    for (int i = 0; i < 8; ++i)
        #pragma unroll
        for (int j = 0; j < 8; ++j) accum[i][j] = 0.f;

    for (int k0 = 0; k0 < K; k0 += 16) {
        #pragma unroll
        for (int i = 0; i < 2; ++i) {
            int f   = tid + i * 256;
            int row = f >> 2;
            int kq  = f & 3;
            float4 a = *(const float4*)(A + (long)(m0 + row) * K + k0 + kq * 4);
            As[kq * 4 + 0][row] = a.x; As[kq * 4 + 1][row] = a.y;
            As[kq * 4 + 2][row] = a.z; As[kq * 4 + 3][row] = a.w;
            float4 b = *(const float4*)(W + (long)(n0 + row) * K + k0 + kq * 4);
            Bs[kq * 4 + 0][row] = b.x; Bs[kq * 4 + 1][row] = b.y;
            Bs[kq * 4 + 2][row] = b.z; Bs[kq * 4 + 3][row] = b.w;
        }
        __syncthreads();
        #pragma unroll
        for (int kk = 0; kk < 16; ++kk) {
            float4 a01 = *(const float4*)&As[kk][ty * 8];
            float4 a23 = *(const float4*)&As[kk][ty * 8 + 4];
            float4 b01 = *(const float4*)&Bs[kk][tx * 8];
            float4 b23 = *(const float4*)&Bs[kk][tx * 8 + 4];
            float av[8] = {a01.x, a01.y, a01.z, a01.w, a23.x, a23.y, a23.z, a23.w};
            float bv[8] = {b01.x, b01.y, b01.z, b01.w, b23.x, b23.y, b23.z, b23.w};
            #pragma unroll
            for (int i = 0; i < 8; ++i)
                #pragma unroll
                for (int j = 0; j < 8; ++j) accum[i][j] += av[i] * bv[j];
        }
        __syncthreads();
    }
    #pragma unroll
    for (int i = 0; i < 8; ++i) {
        float* crow = C + (long)(m0 + ty * 8 + i) * N + n0 + tx * 8;
        const float* brow = bias + n0 + tx * 8;
        float4 o0, o1;
        o0.x = accum[i][0] + brow[0]; o0.y = accum[i][1] + brow[1];
        o0.z = accum[i][2] + brow[2]; o0.w = accum[i][3] + brow[3];
        o1.x = accum[i][4] + brow[4]; o1.y = accum[i][5] + brow[5];
        o1.z = accum[i][6] + brow[6]; o1.w = accum[i][7] + brow[7];
        *(float4*)(crow)     = o0;
        *(float4*)(crow + 4) = o1;
    }
}

// ---------------- persistent GRU v6: 2 independent batch-groups, packed tiles ----------------
// The 32 batches are independent recurrences -> split into 2 groups of 16.
// grp = bid>>7, bid' = bid&127. Each group: 128 blocks x 8 cols, own barrier domain.
// M=16 batches = exactly one MFMA tile (no mt). 3 gates x 8 cols = 24 gate-cols
// packed into 2 16-wide tiles (tile0 = g0|g1 distinct, tile1 = g2 + dup).
// Per-wave MFMAs: 144 -> 48; A-frag LLC loads: 32 -> 16. All 256 CUs used.
__global__ __launch_bounds__(256, 1) void gru_persist(
    float* hs,
    const unsigned short* __restrict__ Whi, const unsigned short* __restrict__ Wlo,
    const float* __restrict__ GIcb, const int* __restrict__ idxi,
    const float* __restrict__ b_hh,
    unsigned short* hA,   // [2 buf][2 grp][hi/lo][32 kk][64 lane][8] ushorts (32KB each part)
    int* slots)           // [2 grp][128] per-block completed-step epochs
{
    __shared__ unsigned short whi0[32][16][32];   // 32 KB: tile0 B-frags (cols 0-7=g0, 8-15=g1)
    __shared__ unsigned short whi1[32][8][32];    // 16 KB: tile1 B-frags (g2)
    __shared__ float red[4][64][9];               // 9.2 KB: k-split partials

    int tid  = threadIdx.x;
    int lane = tid & 63;
    int w    = tid >> 6;
    int bid  = blockIdx.x;
    int grp  = bid >> 7;                  // batch group 0/1 (batches grp*16..grp*16+15)
    int bidp = bid & 127;                 // col-block within group
    int jb   = bidp * 8;
    int q    = lane >> 4;
    int tc   = lane & 15;

    // ---- stage W-hi slice into LDS, once (24 rows x 1024 = 3072 ushort8 -> 12 iters) ----
    for (int it = 0; it < 12; ++it) {
        int u8 = it * 256 + tid;
        int e  = u8 * 8;
        int r24 = e >> 10;
        int k   = e & 1023;
        int g = r24 >> 3, r = r24 & 7;
        s16x8 v = *(const s16x8*)(Whi + (long)((g << 10) + jb + r) * 1024 + k);
        if (g == 0)      *(s16x8*)&whi0[k >> 5][r][k & 31]     = v;
        else if (g == 1) *(s16x8*)&whi0[k >> 5][8 + r][k & 31] = v;
        else             *(s16x8*)&whi1[k >> 5][r][k & 31]     = v;
    }

    // ---- pin W-lo fragments in registers (wave w covers k in [w*256, w*256+256)) ----
    s16x8 wlof[8][2];
    #pragma unroll
    for (int kl = 0; kl < 8; ++kl) {
        int kg = w * 256 + kl * 32 + q * 8;
        int row0 = (tc < 8) ? (jb + tc) : (1024 + jb + (tc - 8));
        wlof[kl][0] = *(const s16x8*)(Wlo + (long)row0 * 1024 + kg);
        wlof[kl][1] = *(const s16x8*)(Wlo + (long)(2048 + jb + (tc & 7)) * 1024 + kg);
    }
    __syncthreads();

    // ---- epilogue constants: thread (tid<128) -> one output (batch ebg, col jg) ----
    int ebg = (tid >> 3) & 15;             // batch-in-group 0..15 (tid>=128 duplicates, unused)
    int eb  = grp * 16 + ebg;              // global batch
    int ejl = tid & 7;                     // j-local 0..7
    int jg  = jb + ejl;
    int eq  = ebg >> 2, eer = ebg & 3;
    float bhr = b_hh[jg], bhz = b_hh[ND + jg], bhn = b_hh[2 * ND + jg];
    // hA write slot (A-frag layout): kk=jg>>5, q'=(jg>>3)&3, e=jg&7, lane'=q'*16+ebg
    int akk = jg >> 5, aqp = (jg >> 3) & 3, aj8 = jg & 7;
    int alane = aqp * 16 + ebg;
    int awoff = (akk * 64 + alane) * 8 + aj8;
    float hp = 0.f;                        // h_prev carried in-register

    #pragma unroll 1
    for (int t = 0; t < NT; ++t) {
        // prefetch gate inputs (barrier-independent, cached reads)
        int cidx = idxi[eb * NT + t];
        const float* gib = GIcb + (long)cidx * NG;
        float gi0 = gib[jg], gi1 = gib[ND + jg], gi2 = gib[2 * ND + jg];

        // all waves poll: all 128 blocks of THIS group completed step t-1 (slot >= t)
        if (t > 0) {
            bool ok;
            do {
                int s1 = __hip_atomic_load(slots + grp * 128 + lane,      __ATOMIC_RELAXED, __HIP_MEMORY_SCOPE_AGENT);
                int s2 = __hip_atomic_load(slots + grp * 128 + 64 + lane, __ATOMIC_RELAXED, __HIP_MEMORY_SCOPE_AGENT);
                ok = (__all((s1 >= t) && (s2 >= t)) != 0);
                if (!ok) __builtin_amdgcn_s_sleep(1);
            } while (!ok);
        }

        const unsigned short* rHi = hA + ((unsigned)((t & 1) * 2 + grp) * 2 + 0) * 16384;
        const unsigned short* rLo = rHi + 16384;
        unsigned short* wHi = hA + ((unsigned)((((t + 1) & 1)) * 2 + grp) * 2 + 0) * 16384;
        unsigned short* wLo = wHi + 16384;

        // ---- issue ALL 16 A-fragment loads (16B each), one waitcnt ----
        s16x8 Ah[8], Al[8];
        #pragma unroll
        for (int kl = 0; kl < 8; ++kl) {
            int kk = w * 8 + kl;
            Ah[kl] = llc_load16(rHi + kk * 512 + lane * 8);
            Al[kl] = llc_load16(rLo + kk * 512 + lane * 8);
        }
        asm volatile("s_waitcnt vmcnt(0)" ::: "memory");

        f32x4 acc0 = (f32x4){0.f, 0.f, 0.f, 0.f};
        f32x4 acc1 = (f32x4){0.f, 0.f, 0.f, 0.f};

        #pragma unroll
        for (int kl = 0; kl < 8; ++kl) {
            int kk = w * 8 + kl;
            s16x8 bh0 = *(const s16x8*)&whi0[kk][tc][q * 8];
            s16x8 bh1 = *(const s16x8*)&whi1[kk][tc & 7][q * 8];
            acc0 = __builtin_amdgcn_mfma_f32_16x16x32_bf16(Ah[kl], bh0, acc0, 0, 0, 0);
            acc1 = __builtin_amdgcn_mfma_f32_16x16x32_bf16(Ah[kl], bh1, acc1, 0, 0, 0);
            acc0 = __builtin_amdgcn_mfma_f32_16x16x32_bf16(Al[kl], bh0, acc0, 0, 0, 0);
            acc1 = __builtin_amdgcn_mfma_f32_16x16x32_bf16(Al[kl], bh1, acc1, 0, 0, 0);
            acc0 = __builtin_amdgcn_mfma_f32_16x16x32_bf16(Ah[kl], wlof[kl][0], acc0, 0, 0, 0);
            acc1 = __builtin_amdgcn_mfma_f32_16x16x32_bf16(Ah[kl], wlof[kl][1], acc1, 0, 0, 0);
        }

        // k-split partials: lane holds C-frag col=tc, rows q*4..q*4+3
        #pragma unroll
        for (int r = 0; r < 4; ++r) {
            red[w][lane][r]     = acc0[r];
            red[w][lane][4 + r] = acc1[r];
        }
        __syncthreads();

        // epilogue: tid<128 -> one output each (16 batches x 8 cols)
        float g0 = 0.f, g1 = 0.f, g2 = 0.f;
        #pragma unroll
        for (int ww = 0; ww < 4; ++ww) {
            g0 += red[ww][eq * 16 + ejl][eer];           // tile0 col ejl   (g0)
            g1 += red[ww][eq * 16 + 8 + ejl][eer];       // tile0 col 8+ejl (g1)
            g2 += red[ww][eq * 16 + ejl][4 + eer];       // tile1 col ejl   (g2)
        }
        if (tid < 128) {
            float xr = gi0 + g0 + bhr;
            float xz = gi1 + g1 + bhz;
            float rg = 1.f / (1.f + __expf(-xr));
            float zg = 1.f / (1.f + __expf(-xz));
            float narg = gi2 + rg * (g2 + bhn);
            float e2 = __expf(2.f * narg);
            float ng = 1.f - 2.f / (e2 + 1.f);
            float hnew = (1.f - zg) * ng + zg * hp;
            hp = hnew;
            hs[((long)eb * NT + t) * ND + jg] = hnew;
            unsigned short hh = f32_to_bf16(hnew);
            unsigned short hl = f32_to_bf16(hnew - bf16_to_f32(hh));
            llc_store2(wHi + awoff, (unsigned int)hh);
            llc_store2(wLo + awoff, (unsigned int)hl);
        }
        asm volatile("s_waitcnt vmcnt(0)" ::: "memory");   // h stores drained to LLC
        __syncthreads();                                   // whole block done
        if (tid == 0)
            llc_store4(slots + grp * 128 + bidp, t + 1);   // relaxed LLC publish, no wbl2
    }
}

// ---------------- CPC loss: one block per (k,l) ----------------
__global__ __launch_bounds__(256) void cp_kernel(
    const float* __restrict__ feat, const float* __restrict__ ctx,
    const int* __restrict__ perm, float* __restrict__ acc)
{
    __shared__ float cx[32][256];
    __shared__ float red2[4];

    int tid = threadIdx.x;
    int bk = blockIdx.x;
    int kk, l;
    if (bk < 511)       { kk = 1; l = bk; }
    else if (bk < 1021) { kk = 2; l = bk - 511; }
    else                { kk = 3; l = bk - 1021; }

    float dacc[5] = {0.f, 0.f, 0.f, 0.f, 0.f};
    for (int c = 0; c < 4; ++c) {
        for (int i = 0; i < 8; ++i) {
            int g = i * 256 + tid;
            int b = g >> 6, kq = g & 63;
            *(float4*)&cx[b][kq * 4] =
                *(const float4*)(ctx + (long)(b * NT + l) * ND + c * 256 + kq * 4);
        }
        __syncthreads();
        for (int oi = 0; oi < 5; ++oi) {
            int o = tid + oi * 256;
            if (o < 1056) {
                int b = o / 33, ii = o % 33;
                const float* frow = (ii < 32)
                    ? (feat + (long)(perm[(kk - 1) * 32 + ii] * NT + l) * ND)
                    : (feat + (long)(b * NT + l + kk) * ND);
                const float4* fp4 = (const float4*)(frow + c * 256);
                const float4* cp4 = (const float4*)&cx[b][0];
                float s = 0.f;
                for (int k4 = 0; k4 < 64; ++k4) {
                    float4 cf = cp4[k4];
                    float4 ff = fp4[k4];
                    s += cf.x * ff.x + cf.y * ff.y + cf.z * ff.z + cf.w * ff.w;
                }
                dacc[oi] += s;
            }
        }
        __syncthreads();
    }

    float nsum = 0.f;
    for (int oi = 0; oi < 5; ++oi) {
        int o = tid + oi * 256;
        if (o < 1056) {
            int b = o / 33, ii = o % 33;
            float x = dacc[oi];
            if (ii < 32) {
                float sn = 1.f / (1.f + expf(x));
                nsum += -logf(sn + 1e-8f);
            } else {
                float sp = 1.f / (1.f + expf(-x));
                atomicAdd(&acc[b], -logf(sp + 1e-8f));
            }
        }
    }
    #pragma unroll
    for (int m = 1; m < 64; m <<= 1) nsum += __shfl_xor(nsum, m, 64);
    if ((tid & 63) == 0) red2[tid >> 6] = nsum;
    __syncthreads();
    if (tid == 0) atomicAdd(&acc[32], red2[0] + red2[1] + red2[2] + red2[3]);
}

// ---------------- finalize ----------------
__global__ void finalize_kernel(const float* __restrict__ acc, float* __restrict__ out) {
    int b = threadIdx.x;
    if (b < 32) {
        float cp = (acc[b] + 0.25f * acc[32] * (1.0f / 1024.0f)) * (1.0f / 1527.0f);
        float vq = 1.25f * acc[33] * (1.0f / 16777216.0f);
        out[b] = cp + vq;
    }
}

// ---------------- launch ----------------
extern "C" void kernel_launch(void* const* d_in, const int* in_sizes, int n_in,
                              void* d_out, int out_size, void* d_ws, size_t ws_size,
                              hipStream_t stream)
{
    const float* feat   = (const float*)d_in[0];
    const float* cb     = (const float*)d_in[1];
    const float* W_ih   = (const float*)d_in[2];
    const float* W_hh   = (const float*)d_in[3];
    const float* b_ih   = (const float*)d_in[4];
    const float* b_hh   = (const float*)d_in[5];
    const float* W_proj = (const float*)d_in[6];
    const float* b_proj = (const float*)d_in[7];
    const int*   nperm  = (const int*)d_in[8];

    float* outq    = (float*)d_out;
    float* outidx  = outq + 16777216;
    float* outloss = outq + 16793600;

    char* ws = (char*)d_ws;
    float*          hs   = (float*)(ws);                        //  67,108,864 B
    float*          ctx  = (float*)(ws + 67108864);             //  67,108,864 B
    unsigned short* Whi  = (unsigned short*)(ws + 134217728);   //   6,291,456 B
    unsigned short* Wlo  = (unsigned short*)(ws + 140509184);   //   6,291,456 B
    float*          GIcb = (float*)(ws + 146800640);            //   3,145,728 B
    int*            idxi = (int*)(ws + 149946368);              //      65,536 B
    float*          acc  = (float*)(ws + 150011904);            //  256 B acc
    int*            slots= (int*)(ws + 150012160);              //  1024 B barrier slots (2 grp x 128)
    unsigned short* hA   = (unsigned short*)(ws + 150013184);   //  262,144 B h frag bufs

    // zero acc (256) + slots (1024) + hA buffer 0 hi+lo both groups (131072): one memset
    hipMemsetAsync(acc, 0, 256 + 1024 + 131072, stream);
    prep_w<<<12288, 256, 0, stream>>>(W_hh, Whi, Wlo);
    quantize_kernel<<<2048, 256, 0, stream>>>(feat, cb, outq, outidx, idxi, acc);
    // GIcb = codebook @ W_ih^T + b_ih  (256x3072, K=1024)
    gemm_nt<<<dim3(24, 2), 256, 0, stream>>>(cb, W_ih, b_ih, GIcb, NG, ND);
    // persistent GRU: one launch, 512 in-kernel steps, 2 independent batch-groups
    gru_persist<<<GRU_BLOCKS, 256, 0, stream>>>(hs, Whi, Wlo, GIcb, idxi, b_hh, hA, slots);
    // context_proj = hs @ W_proj^T + b_proj
    gemm_nt<<<dim3(8, 128), 256, 0, stream>>>(hs, W_proj, b_proj, ctx, ND, ND);
    cp_kernel<<<1530, 256, 0, stream>>>(feat, ctx, nperm, acc);
    finalize_kernel<<<1, 64, 0, stream>>>(acc, outloss);
}

// Round 3
// 3509.973 us; speedup vs baseline: 1.8154x; 1.0673x over previous
//
#include <hip/hip_runtime.h>
#include <stdint.h>

// Problem constants (fixed by reference): B=32, T=512, d=1024, Kcb=256
#define NB    32
#define NT    512
#define ND    1024
#define NG    3072      // 3*d
#define NROW  16384     // B*T
#define KCB   256
#define GRU_BLOCKS 256  // 2 independent batch-groups x 128 col-blocks

typedef float  f32x4 __attribute__((ext_vector_type(4)));
typedef short  s16x8 __attribute__((ext_vector_type(8)));

// ---------------- bf16 helpers (hi/lo split precision) ----------------
__device__ __forceinline__ unsigned short f32_to_bf16(float x) {
    union { float f; unsigned int u; } v; v.f = x;
    unsigned int u = v.u;
    return (unsigned short)((u + 0x7FFFu + ((u >> 16) & 1u)) >> 16);
}
__device__ __forceinline__ float bf16_to_f32(unsigned short h) {
    union { float f; unsigned int u; } v; v.u = ((unsigned int)h) << 16; return v.f;
}

// LLC-coherent (L1/L2-bypassing) 16B load / 2B store — cross-XCD fresh without fences.
__device__ __forceinline__ s16x8 llc_load16(const unsigned short* p) {
    s16x8 r;
    asm volatile("global_load_dwordx4 %0, %1, off sc0 sc1" : "=v"(r) : "v"(p) : "memory");
    return r;
}
__device__ __forceinline__ void llc_store2(unsigned short* p, unsigned int v) {
    asm volatile("global_store_short %0, %1, off sc0 sc1" :: "v"(p), "v"(v) : "memory");
}
// Relaxed LLC-level 4B store: publishes the step slot WITHOUT the agent-release
// buffer_wbl2 (full L2 dirty writeback + drain) that __hip_atomic_store(RELEASE,
// AGENT) emits. Ordering vs the hA data is already guaranteed: hA is written with
// sc0|sc1 write-through stores drained by s_waitcnt vmcnt(0) before this store.
__device__ __forceinline__ void llc_store4(int* p, int v) {
    asm volatile("global_store_dword %0, %1, off sc0 sc1" :: "v"(p), "v"(v) : "memory");
}

// ---------------- W -> bf16 hi/lo split (once per launch; grid sized = elems/256) ----------------
__global__ __launch_bounds__(256) void prep_w(const float* __restrict__ W,
                                              unsigned short* __restrict__ Whi,
                                              unsigned short* __restrict__ Wlo) {
    int i = blockIdx.x * 256 + threadIdx.x;
    float w = W[i];
    unsigned short hi = f32_to_bf16(w);
    float rem = w - bf16_to_f32(hi);
    Whi[i] = hi;
    Wlo[i] = f32_to_bf16(rem);
}

// ---------------- quantize: fp64 scores, argmin, copy row, SSD ----------------
__global__ __launch_bounds__(256) void quantize_kernel(
    const float* __restrict__ feat, const float* __restrict__ cb,
    float* __restrict__ out_q, float* __restrict__ out_idx,
    int* __restrict__ idxi, float* __restrict__ acc)
{
    __shared__ float  fr[8][1024];     // 32 KB
    __shared__ double wsco[4];
    __shared__ int    wid[4];
    __shared__ int    winner;
    __shared__ float  sp[4];

    int tid = threadIdx.x;
    int r0  = blockIdx.x * 8;

    for (int i = 0; i < 8; ++i) {
        int g   = i * 256 + tid;
        int row = g >> 8;
        int kq  = g & 255;
        float4 v = ((const float4*)(feat + (long)(r0 + row) * ND))[kq];
        ((float4*)&fr[row][0])[kq] = v;
    }
    __syncthreads();

    double dot[8];
    #pragma unroll
    for (int r = 0; r < 8; ++r) dot[r] = 0.0;
    double cc = 0.0;
    const float4* cbrow = (const float4*)(cb + (long)tid * ND);
    for (int k4 = 0; k4 < 256; ++k4) {
        float4 c = cbrow[k4];
        cc += (double)c.x * (double)c.x + (double)c.y * (double)c.y
            + (double)c.z * (double)c.z + (double)c.w * (double)c.w;
        #pragma unroll
        for (int r = 0; r < 8; ++r) {
            float4 f = ((const float4*)&fr[r][0])[k4];
            dot[r] += (double)(f.x * c.x) + (double)(f.y * c.y)
                    + (double)(f.z * c.z) + (double)(f.w * c.w);
        }
    }

    float ssd_thread = 0.f;
    for (int r = 0; r < 8; ++r) {
        double s = cc - 2.0 * dot[r];
        int idx = tid;
        #pragma unroll
        for (int m = 1; m < 64; m <<= 1) {
            double s2 = __shfl_xor(s, m, 64);
            int    i2 = __shfl_xor(idx, m, 64);
            if (s2 < s || (s2 == s && i2 < idx)) { s = s2; idx = i2; }
        }
        int w = tid >> 6;
        if ((tid & 63) == 0) { wsco[w] = s; wid[w] = idx; }
        __syncthreads();
        if (tid == 0) {
            double bs = wsco[0]; int bi = wid[0];
            for (int w2 = 1; w2 < 4; ++w2)
                if (wsco[w2] < bs || (wsco[w2] == bs && wid[w2] < bi)) { bs = wsco[w2]; bi = wid[w2]; }
            winner = bi;
            out_idx[r0 + r] = (float)bi;
            idxi[r0 + r]    = bi;
        }
        __syncthreads();
        int win = winner;
        float4 q = ((const float4*)(cb + (long)win * ND))[tid];
        ((float4*)(out_q + (long)(r0 + r) * ND))[tid] = q;
        float4 f = ((const float4*)&fr[r][0])[tid];
        float dx = f.x - q.x, dy = f.y - q.y, dz = f.z - q.z, dw = f.w - q.w;
        ssd_thread += dx * dx + dy * dy + dz * dz + dw * dw;
        __syncthreads();
    }

    #pragma unroll
    for (int m = 1; m < 64; m <<= 1) ssd_thread += __shfl_xor(ssd_thread, m, 64);
    if ((tid & 63) == 0) sp[tid >> 6] = ssd_thread;
    __syncthreads();
    if (tid == 0) atomicAdd(&acc[33], sp[0] + sp[1] + sp[2] + sp[3]);
}

// ---------------- fp32 tiled GEMM: C[M,N] = A[M,K] * W[N,K]^T + bias[N] ----------------
// (only used for the small GIcb = cb @ W_ih^T now)
__global__ __launch_bounds__(256) void gemm_nt(
    const float* __restrict__ A, const float* __restrict__ W,
    const float* __restrict__ bias, float* __restrict__ C, int N, int K)
{
    __shared__ float As[16][132];
    __shared__ float Bs[16][132];
    int tid = threadIdx.x;
    int m0 = blockIdx.y * 128;
    int n0 = blockIdx.x * 128;
    int tx = tid & 15, ty = tid >> 4;

    float accum[8][8];
    #pragma unroll
    for (int i = 0; i < 8; ++i)
        #pragma unroll
        for (int j = 0; j < 8; ++j) accum[i][j] = 0.f;

    for (int k0 = 0; k0 < K; k0 += 16) {
        #pragma unroll
        for (int i = 0; i < 2; ++i) {
            int f   = tid + i * 256;
            int row = f >> 2;
            int kq  = f & 3;
            float4 a = *(const float4*)(A + (long)(m0 + row) * K + k0 + kq * 4);
            As[kq * 4 + 0][row] = a.x; As[kq * 4 + 1][row] = a.y;
            As[kq * 4 + 2][row] = a.z; As[kq * 4 + 3][row] = a.w;
            float4 b = *(const float4*)(W + (long)(n0 + row) * K + k0 + kq * 4);
            Bs[kq * 4 + 0][row] = b.x; Bs[kq * 4 + 1][row] = b.y;
            Bs[kq * 4 + 2][row] = b.z; Bs[kq * 4 + 3][row] = b.w;
        }
        __syncthreads();
        #pragma unroll
        for (int kk = 0; kk < 16; ++kk) {
            float4 a01 = *(const float4*)&As[kk][ty * 8];
            float4 a23 = *(const float4*)&As[kk][ty * 8 + 4];
            float4 b01 = *(const float4*)&Bs[kk][tx * 8];
            float4 b23 = *(const float4*)&Bs[kk][tx * 8 + 4];
            float av[8] = {a01.x, a01.y, a01.z, a01.w, a23.x, a23.y, a23.z, a23.w};
            float bv[8] = {b01.x, b01.y, b01.z, b01.w, b23.x, b23.y, b23.z, b23.w};
            #pragma unroll
            for (int i = 0; i < 8; ++i)
                #pragma unroll
                for (int j = 0; j < 8; ++j) accum[i][j] += av[i] * bv[j];
        }
        __syncthreads();
    }
    #pragma unroll
    for (int i = 0; i < 8; ++i) {
        float* crow = C + (long)(m0 + ty * 8 + i) * N + n0 + tx * 8;
        const float* brow = bias + n0 + tx * 8;
        float4 o0, o1;
        o0.x = accum[i][0] + brow[0]; o0.y = accum[i][1] + brow[1];
        o0.z = accum[i][2] + brow[2]; o0.w = accum[i][3] + brow[3];
        o1.x = accum[i][4] + brow[4]; o1.y = accum[i][5] + brow[5];
        o1.z = accum[i][6] + brow[6]; o1.w = accum[i][7] + brow[7];
        *(float4*)(crow)     = o0;
        *(float4*)(crow + 4) = o1;
    }
}

// ---------------- persistent GRU v7: ctx fused into tile1's spare half ----------------
// 2 groups of 16 batches; 128 col-blocks each owning 8 j-cols. tile0 = [g0|g1]
// (16 distinct cols). tile1 = [g2 | W_proj] — the previously-duplicated half of
// tile1 now carries W_proj rows, so ctx[b,t-1] = h(t-1) @ W_proj^T falls out of
// the SAME 48 MFMAs/wave (A-frags = h hi/lo are already loaded for the gates).
// One extra pseudo-step (t = NT) consumes h(NT-1)'s frags to emit ctx[:,NT-1].
// This deletes the separate 16384x1024x1024 fp32 ctx GEMM and the hs array.
__global__ __launch_bounds__(256, 1) void gru_persist(
    float* ctxp,
    const unsigned short* __restrict__ Whi, const unsigned short* __restrict__ Wlo,
    const unsigned short* __restrict__ Phi, const unsigned short* __restrict__ Plo,
    const float* __restrict__ GIcb, const int* __restrict__ idxi,
    const float* __restrict__ b_hh, const float* __restrict__ b_proj,
    unsigned short* hA,   // [2 buf][2 grp][hi/lo][32 kk][64 lane][8] ushorts
    int* slots)           // [2 grp][128] per-block completed-step epochs
{
    __shared__ unsigned short whi0[32][16][32];   // 32 KB: tile0 (cols 0-7=g0, 8-15=g1)
    __shared__ unsigned short whi1[32][16][32];   // 32 KB: tile1 (cols 0-7=g2, 8-15=W_proj)
    __shared__ float red[4][64][9];               // 9.2 KB: k-split partials

    int tid  = threadIdx.x;
    int lane = tid & 63;
    int w    = tid >> 6;
    int bid  = blockIdx.x;
    int grp  = bid >> 7;                  // batch group 0/1 (batches grp*16..grp*16+15)
    int bidp = bid & 127;                 // col-block within group
    int jb   = bidp * 8;
    int q    = lane >> 4;
    int tc   = lane & 15;

    // ---- stage W-hi slices into LDS, once (32 rows x 1024 = 4096 ushort8 -> 16 iters) ----
    for (int it = 0; it < 16; ++it) {
        int u8  = it * 256 + tid;          // 0..4095
        int r32 = u8 >> 7;                 // virtual row 0..31
        int k   = (u8 & 127) * 8;          // k offset
        int g = r32 >> 3, r = r32 & 7;     // g: 0=g0,1=g1,2=g2,3=W_proj
        const unsigned short* src = (g < 3)
            ? (Whi + (long)((g << 10) + jb + r) * 1024 + k)
            : (Phi + (long)(jb + r) * 1024 + k);
        s16x8 v = *(const s16x8*)src;
        if (g == 0)      *(s16x8*)&whi0[k >> 5][r][k & 31]     = v;
        else if (g == 1) *(s16x8*)&whi0[k >> 5][8 + r][k & 31] = v;
        else if (g == 2) *(s16x8*)&whi1[k >> 5][r][k & 31]     = v;
        else             *(s16x8*)&whi1[k >> 5][8 + r][k & 31] = v;
    }

    // ---- pin W-lo fragments in registers (wave w covers k in [w*256, w*256+256)) ----
    s16x8 wlof[8][2];
    #pragma unroll
    for (int kl = 0; kl < 8; ++kl) {
        int kg = w * 256 + kl * 32 + q * 8;
        int row0 = (tc < 8) ? (jb + tc) : (1024 + jb + (tc - 8));
        wlof[kl][0] = *(const s16x8*)(Wlo + (long)row0 * 1024 + kg);
        wlof[kl][1] = (tc < 8)
            ? *(const s16x8*)(Wlo + (long)(2048 + jb + tc) * 1024 + kg)
            : *(const s16x8*)(Plo + (long)(jb + (tc - 8)) * 1024 + kg);
    }
    __syncthreads();

    // ---- epilogue constants: thread (tid<128) -> one output (batch ebg, col jg) ----
    int ebg = (tid >> 3) & 15;             // batch-in-group 0..15
    int eb  = grp * 16 + ebg;              // global batch
    int ejl = tid & 7;                     // j-local 0..7
    int jg  = jb + ejl;
    int eq  = ebg >> 2, eer = ebg & 3;
    float bhr = b_hh[jg], bhz = b_hh[ND + jg], bhn = b_hh[2 * ND + jg];
    float bpj = b_proj[jg];
    // hA write slot (A-frag layout): kk=jg>>5, q'=(jg>>3)&3, e=jg&7, lane'=q'*16+ebg
    int akk = jg >> 5, aqp = (jg >> 3) & 3, aj8 = jg & 7;
    int alane = aqp * 16 + ebg;
    int awoff = (akk * 64 + alane) * 8 + aj8;
    float hp = 0.f;                        // h_prev carried in-register

    #pragma unroll 1
    for (int t = 0; t <= NT; ++t) {
        // prefetch gate inputs (barrier-independent, cached reads; clamp at pseudo-step)
        int tcl = (t < NT) ? t : (NT - 1);
        int cidx = idxi[eb * NT + tcl];
        const float* gib = GIcb + (long)cidx * NG;
        float gi0 = gib[jg], gi1 = gib[ND + jg], gi2 = gib[2 * ND + jg];

        // all waves poll: all 128 blocks of THIS group completed step t-1 (slot >= t)
        if (t > 0) {
            bool ok;
            do {
                int s1 = __hip_atomic_load(slots + grp * 128 + lane,      __ATOMIC_RELAXED, __HIP_MEMORY_SCOPE_AGENT);
                int s2 = __hip_atomic_load(slots + grp * 128 + 64 + lane, __ATOMIC_RELAXED, __HIP_MEMORY_SCOPE_AGENT);
                ok = (__all((s1 >= t) && (s2 >= t)) != 0);
                if (!ok) __builtin_amdgcn_s_sleep(1);
            } while (!ok);
        }

        const unsigned short* rHi = hA + ((unsigned)((t & 1) * 2 + grp) * 2 + 0) * 16384;
        const unsigned short* rLo = rHi + 16384;
        unsigned short* wHi = hA + ((unsigned)((((t + 1) & 1)) * 2 + grp) * 2 + 0) * 16384;
        unsigned short* wLo = wHi + 16384;

        // ---- issue ALL 16 A-fragment loads (16B each), one waitcnt ----
        s16x8 Ah[8], Al[8];
        #pragma unroll
        for (int kl = 0; kl < 8; ++kl) {
            int kk = w * 8 + kl;
            Ah[kl] = llc_load16(rHi + kk * 512 + lane * 8);
            Al[kl] = llc_load16(rLo + kk * 512 + lane * 8);
        }
        asm volatile("s_waitcnt vmcnt(0)" ::: "memory");

        f32x4 acc0 = (f32x4){0.f, 0.f, 0.f, 0.f};
        f32x4 acc1 = (f32x4){0.f, 0.f, 0.f, 0.f};

        #pragma unroll
        for (int kl = 0; kl < 8; ++kl) {
            int kk = w * 8 + kl;
            s16x8 bh0 = *(const s16x8*)&whi0[kk][tc][q * 8];
            s16x8 bh1 = *(const s16x8*)&whi1[kk][tc][q * 8];
            acc0 = __builtin_amdgcn_mfma_f32_16x16x32_bf16(Ah[kl], bh0, acc0, 0, 0, 0);
            acc1 = __builtin_amdgcn_mfma_f32_16x16x32_bf16(Ah[kl], bh1, acc1, 0, 0, 0);
            acc0 = __builtin_amdgcn_mfma_f32_16x16x32_bf16(Al[kl], bh0, acc0, 0, 0, 0);
            acc1 = __builtin_amdgcn_mfma_f32_16x16x32_bf16(Al[kl], bh1, acc1, 0, 0, 0);
            acc0 = __builtin_amdgcn_mfma_f32_16x16x32_bf16(Ah[kl], wlof[kl][0], acc0, 0, 0, 0);
            acc1 = __builtin_amdgcn_mfma_f32_16x16x32_bf16(Ah[kl], wlof[kl][1], acc1, 0, 0, 0);
        }

        // k-split partials: lane holds C-frag col=tc, rows q*4..q*4+3
        #pragma unroll
        for (int r = 0; r < 4; ++r) {
            red[w][lane][r]     = acc0[r];
            red[w][lane][4 + r] = acc1[r];
        }
        __syncthreads();

        // epilogue: tid<128 -> one output each (16 batches x 8 cols)
        float g0 = 0.f, g1 = 0.f, g2 = 0.f, cx = 0.f;
        #pragma unroll
        for (int ww = 0; ww < 4; ++ww) {
            g0 += red[ww][eq * 16 + ejl][eer];           // tile0 col ejl    (g0)
            g1 += red[ww][eq * 16 + 8 + ejl][eer];       // tile0 col 8+ejl  (g1)
            g2 += red[ww][eq * 16 + ejl][4 + eer];       // tile1 col ejl    (g2)
            cx += red[ww][eq * 16 + 8 + ejl][4 + eer];   // tile1 col 8+ejl  (ctx partial)
        }
        if (tid < 128) {
            if (t > 0) {
                // ctx row t-1: A-frags this step were h(t-1)
                ctxp[((long)eb * NT + (t - 1)) * ND + jg] = cx + bpj;
            }
            if (t < NT) {
                float xr = gi0 + g0 + bhr;
                float xz = gi1 + g1 + bhz;
                float rg = 1.f / (1.f + __expf(-xr));
                float zg = 1.f / (1.f + __expf(-xz));
                float narg = gi2 + rg * (g2 + bhn);
                float e2 = __expf(2.f * narg);
                float ng = 1.f - 2.f / (e2 + 1.f);
                float hnew = (1.f - zg) * ng + zg * hp;
                hp = hnew;
                unsigned short hh = f32_to_bf16(hnew);
                unsigned short hl = f32_to_bf16(hnew - bf16_to_f32(hh));
                llc_store2(wHi + awoff, (unsigned int)hh);
                llc_store2(wLo + awoff, (unsigned int)hl);
            }
        }
        if (t < NT) {
            asm volatile("s_waitcnt vmcnt(0)" ::: "memory");   // h stores drained to LLC
            __syncthreads();                                   // whole block done
            if (tid == 0)
                llc_store4(slots + grp * 128 + bidp, t + 1);   // relaxed LLC publish
        }
    }
}

// ---------------- CPC loss: one block per (k,l) ----------------
__global__ __launch_bounds__(256) void cp_kernel(
    const float* __restrict__ feat, const float* __restrict__ ctx,
    const int* __restrict__ perm, float* __restrict__ acc)
{
    __shared__ float cx[32][256];
    __shared__ float red2[4];

    int tid = threadIdx.x;
    int bk = blockIdx.x;
    int kk, l;
    if (bk < 511)       { kk = 1; l = bk; }
    else if (bk < 1021) { kk = 2; l = bk - 511; }
    else                { kk = 3; l = bk - 1021; }

    float dacc[5] = {0.f, 0.f, 0.f, 0.f, 0.f};
    for (int c = 0; c < 4; ++c) {
        for (int i = 0; i < 8; ++i) {
            int g = i * 256 + tid;
            int b = g >> 6, kq = g & 63;
            *(float4*)&cx[b][kq * 4] =
                *(const float4*)(ctx + (long)(b * NT + l) * ND + c * 256 + kq * 4);
        }
        __syncthreads();
        for (int oi = 0; oi < 5; ++oi) {
            int o = tid + oi * 256;
            if (o < 1056) {
                int b = o / 33, ii = o % 33;
                const float* frow = (ii < 32)
                    ? (feat + (long)(perm[(kk - 1) * 32 + ii] * NT + l) * ND)
                    : (feat + (long)(b * NT + l + kk) * ND);
                const float4* fp4 = (const float4*)(frow + c * 256);
                const float4* cp4 = (const float4*)&cx[b][0];
                float s = 0.f;
                for (int k4 = 0; k4 < 64; ++k4) {
                    float4 cf = cp4[k4];
                    float4 ff = fp4[k4];
                    s += cf.x * ff.x + cf.y * ff.y + cf.z * ff.z + cf.w * ff.w;
                }
                dacc[oi] += s;
            }
        }
        __syncthreads();
    }

    float nsum = 0.f;
    for (int oi = 0; oi < 5; ++oi) {
        int o = tid + oi * 256;
        if (o < 1056) {
            int b = o / 33, ii = o % 33;
            float x = dacc[oi];
            if (ii < 32) {
                float sn = 1.f / (1.f + expf(x));
                nsum += -logf(sn + 1e-8f);
            } else {
                float sp = 1.f / (1.f + expf(-x));
                atomicAdd(&acc[b], -logf(sp + 1e-8f));
            }
        }
    }
    #pragma unroll
    for (int m = 1; m < 64; m <<= 1) nsum += __shfl_xor(nsum, m, 64);
    if ((tid & 63) == 0) red2[tid >> 6] = nsum;
    __syncthreads();
    if (tid == 0) atomicAdd(&acc[32], red2[0] + red2[1] + red2[2] + red2[3]);
}

// ---------------- finalize ----------------
__global__ void finalize_kernel(const float* __restrict__ acc, float* __restrict__ out) {
    int b = threadIdx.x;
    if (b < 32) {
        float cp = (acc[b] + 0.25f * acc[32] * (1.0f / 1024.0f)) * (1.0f / 1527.0f);
        float vq = 1.25f * acc[33] * (1.0f / 16777216.0f);
        out[b] = cp + vq;
    }
}

// ---------------- launch ----------------
extern "C" void kernel_launch(void* const* d_in, const int* in_sizes, int n_in,
                              void* d_out, int out_size, void* d_ws, size_t ws_size,
                              hipStream_t stream)
{
    const float* feat   = (const float*)d_in[0];
    const float* cb     = (const float*)d_in[1];
    const float* W_ih   = (const float*)d_in[2];
    const float* W_hh   = (const float*)d_in[3];
    const float* b_ih   = (const float*)d_in[4];
    const float* b_hh   = (const float*)d_in[5];
    const float* W_proj = (const float*)d_in[6];
    const float* b_proj = (const float*)d_in[7];
    const int*   nperm  = (const int*)d_in[8];

    float* outq    = (float*)d_out;
    float* outidx  = outq + 16777216;
    float* outloss = outq + 16793600;

    char* ws = (char*)d_ws;
    float*          ctx  = (float*)(ws);                       //  67,108,864 B
    unsigned short* Whi  = (unsigned short*)(ws + 67108864);   //   6,291,456 B
    unsigned short* Wlo  = (unsigned short*)(ws + 73400320);   //   6,291,456 B
    unsigned short* Phi  = (unsigned short*)(ws + 79691776);   //   2,097,152 B
    unsigned short* Plo  = (unsigned short*)(ws + 81788928);   //   2,097,152 B
    float*          GIcb = (float*)(ws + 83886080);            //   3,145,728 B
    int*            idxi = (int*)(ws + 87031808);              //      65,536 B
    float*          acc  = (float*)(ws + 87097344);            //  256 B acc
    int*            slots= (int*)(ws + 87097600);              //  1024 B barrier slots
    unsigned short* hA   = (unsigned short*)(ws + 87098624);   //  262,144 B h frag bufs

    // zero acc (256) + slots (1024) + hA buffer 0 hi+lo both groups (131072): one memset
    hipMemsetAsync(acc, 0, 256 + 1024 + 131072, stream);
    prep_w<<<12288, 256, 0, stream>>>(W_hh, Whi, Wlo);
    prep_w<<<4096, 256, 0, stream>>>(W_proj, Phi, Plo);
    quantize_kernel<<<2048, 256, 0, stream>>>(feat, cb, outq, outidx, idxi, acc);
    // GIcb = codebook @ W_ih^T + b_ih  (256x3072, K=1024)
    gemm_nt<<<dim3(24, 2), 256, 0, stream>>>(cb, W_ih, b_ih, GIcb, NG, ND);
    // persistent GRU: 513 in-kernel steps, ctx fused (tile1 cols 8-15 = W_proj)
    gru_persist<<<GRU_BLOCKS, 256, 0, stream>>>(ctx, Whi, Wlo, Phi, Plo, GIcb, idxi,
                                                b_hh, b_proj, hA, slots);
    cp_kernel<<<1530, 256, 0, stream>>>(feat, ctx, nperm, acc);
    finalize_kernel<<<1, 64, 0, stream>>>(acc, outloss);
}

// Round 4
// 2911.009 us; speedup vs baseline: 2.1889x; 1.2058x over previous
//
#include <hip/hip_runtime.h>
#include <stdint.h>

// Problem constants (fixed by reference): B=32, T=512, d=1024, Kcb=256
#define NB    32
#define NT    512
#define ND    1024
#define NG    3072      // 3*d
#define NROW  16384     // B*T
#define KCB   256
#define GRU_BLOCKS 256  // 2 independent batch-groups x 128 col-blocks

typedef float  f32x4 __attribute__((ext_vector_type(4)));
typedef short  s16x8 __attribute__((ext_vector_type(8)));

// ---------------- bf16 helpers (hi/lo split precision) ----------------
__device__ __forceinline__ unsigned short f32_to_bf16(float x) {
    union { float f; unsigned int u; } v; v.f = x;
    unsigned int u = v.u;
    return (unsigned short)((u + 0x7FFFu + ((u >> 16) & 1u)) >> 16);
}
__device__ __forceinline__ float bf16_to_f32(unsigned short h) {
    union { float f; unsigned int u; } v; v.u = ((unsigned int)h) << 16; return v.f;
}

// LLC-coherent (L1/L2-bypassing) 16B load / 2B store — cross-XCD fresh without fences.
__device__ __forceinline__ s16x8 llc_load16(const unsigned short* p) {
    s16x8 r;
    asm volatile("global_load_dwordx4 %0, %1, off sc0 sc1" : "=v"(r) : "v"(p) : "memory");
    return r;
}
__device__ __forceinline__ void llc_store2(unsigned short* p, unsigned int v) {
    asm volatile("global_store_short %0, %1, off sc0 sc1" :: "v"(p), "v"(v) : "memory");
}
// Relaxed LLC-level 4B store: publishes the step slot WITHOUT the agent-release
// buffer_wbl2 (full L2 writeback + drain) that RELEASE/AGENT atomics emit.
__device__ __forceinline__ void llc_store4(int* p, int v) {
    asm volatile("global_store_dword %0, %1, off sc0 sc1" :: "v"(p), "v"(v) : "memory");
}

// ---------------- W -> bf16 hi/lo split (grid sized = elems/256) ----------------
__global__ __launch_bounds__(256) void prep_w(const float* __restrict__ W,
                                              unsigned short* __restrict__ Whi,
                                              unsigned short* __restrict__ Wlo) {
    int i = blockIdx.x * 256 + threadIdx.x;
    float w = W[i];
    unsigned short hi = f32_to_bf16(w);
    float rem = w - bf16_to_f32(hi);
    Whi[i] = hi;
    Wlo[i] = f32_to_bf16(rem);
}

// ---------------- vectorized hi/lo split: 8 elems/thread (grid = elems/2048) ----------------
__global__ __launch_bounds__(256) void prep_split(const float* __restrict__ X,
                                                  unsigned short* __restrict__ Hi,
                                                  unsigned short* __restrict__ Lo) {
    long i8 = ((long)blockIdx.x * 256 + threadIdx.x) * 8;
    float4 a = *(const float4*)(X + i8);
    float4 b = *(const float4*)(X + i8 + 4);
    float xs[8] = {a.x, a.y, a.z, a.w, b.x, b.y, b.z, b.w};
    s16x8 hi, lo;
    #pragma unroll
    for (int j = 0; j < 8; ++j) {
        unsigned short h = f32_to_bf16(xs[j]);
        hi[j] = (short)h;
        lo[j] = (short)f32_to_bf16(xs[j] - bf16_to_f32(h));
    }
    *(s16x8*)(Hi + i8) = hi;
    *(s16x8*)(Lo + i8) = lo;
}

// ---------------- ||c||^2 in fp64, once (1 block, 256 threads) ----------------
__global__ __launch_bounds__(256) void cc_kernel(const float* __restrict__ cb,
                                                 float* __restrict__ ccg) {
    int c = threadIdx.x;
    const float4* row = (const float4*)(cb + (long)c * ND);
    double s = 0.0;
    for (int i = 0; i < 256; ++i) {
        float4 v = row[i];
        s += (double)v.x * (double)v.x + (double)v.y * (double)v.y
           + (double)v.z * (double)v.z + (double)v.w * (double)v.w;
    }
    ccg[c] = (float)s;
}

// ---------------- MFMA quantize: bf16 hi/lo 3-pass dots, argmin, copy, SSD ----------------
// 256 blocks x 64 rows. argmin over c of (||c||^2 - 2 f.c). dot error ~1.6e-5,
// ~15x below the margin floor implied by the fp32 JAX reference matching exact fp64.
// A/B/C fragment layouts identical to the verified gru kernel (lane&15 = M/N idx,
// k = (lane>>4)*8 + 32*kfrag; C: col=lane&15, row=(lane>>4)*4+reg).
__global__ __launch_bounds__(256, 1) void quantize_mfma(
    const float* __restrict__ feat, const float* __restrict__ cb,
    const unsigned short* __restrict__ fHi, const unsigned short* __restrict__ fLo,
    const unsigned short* __restrict__ cHi, const unsigned short* __restrict__ cLo,
    const float* __restrict__ ccg,
    float* __restrict__ out_q, float* __restrict__ out_idx,
    int* __restrict__ idxi, float* __restrict__ acc)
{
    __shared__ unsigned short cbsH[256][64];   // 32 KB, k XOR-swizzled
    __shared__ unsigned short cbsL[256][64];   // 32 KB
    __shared__ float ccs[256];
    __shared__ int   widx[64];
    __shared__ float sp[4];

    int tid  = threadIdx.x;
    int lane = tid & 63;
    int w    = tid >> 6;
    int r0   = blockIdx.x * 64;
    int tm   = lane & 15;          // M-row / N-col within tile
    int q    = lane >> 4;          // k sub-chunk

    ccs[tid] = ccg[tid];

    f32x4 dacc[16];
    #pragma unroll
    for (int n = 0; n < 16; ++n) dacc[n] = (f32x4){0.f, 0.f, 0.f, 0.f};

    const long arow = (long)(r0 + w * 16 + tm) * ND;

    for (int kc = 0; kc < 16; ++kc) {
        int k0 = kc * 64;
        // stage codebook chunk [256 codes][64 k] hi+lo, XOR-swizzled in k
        #pragma unroll
        for (int it = 0; it < 8; ++it) {
            int u    = it * 256 + tid;        // 0..2047
            int code = u >> 3;
            int j8   = u & 7;
            int ksw  = (j8 * 8) ^ ((code & 7) << 3);
            *(s16x8*)&cbsH[code][ksw] = *(const s16x8*)(cHi + (long)code * ND + k0 + j8 * 8);
            *(s16x8*)&cbsL[code][ksw] = *(const s16x8*)(cLo + (long)code * ND + k0 + j8 * 8);
        }
        // A-frags direct from global (independent of staging)
        s16x8 ah0 = *(const s16x8*)(fHi + arow + k0 + q * 8);
        s16x8 ah1 = *(const s16x8*)(fHi + arow + k0 + 32 + q * 8);
        s16x8 al0 = *(const s16x8*)(fLo + arow + k0 + q * 8);
        s16x8 al1 = *(const s16x8*)(fLo + arow + k0 + 32 + q * 8);
        __syncthreads();
        int ksw0 = (q * 8) ^ ((tm & 7) << 3);
        int ksw1 = (32 + q * 8) ^ ((tm & 7) << 3);
        #pragma unroll
        for (int n = 0; n < 16; ++n) {
            s16x8 bh0 = *(const s16x8*)&cbsH[n * 16 + tm][ksw0];
            s16x8 bh1 = *(const s16x8*)&cbsH[n * 16 + tm][ksw1];
            s16x8 bl0 = *(const s16x8*)&cbsL[n * 16 + tm][ksw0];
            s16x8 bl1 = *(const s16x8*)&cbsL[n * 16 + tm][ksw1];
            dacc[n] = __builtin_amdgcn_mfma_f32_16x16x32_bf16(ah0, bh0, dacc[n], 0, 0, 0);
            dacc[n] = __builtin_amdgcn_mfma_f32_16x16x32_bf16(al0, bh0, dacc[n], 0, 0, 0);
            dacc[n] = __builtin_amdgcn_mfma_f32_16x16x32_bf16(ah0, bl0, dacc[n], 0, 0, 0);
            dacc[n] = __builtin_amdgcn_mfma_f32_16x16x32_bf16(ah1, bh1, dacc[n], 0, 0, 0);
            dacc[n] = __builtin_amdgcn_mfma_f32_16x16x32_bf16(al1, bh1, dacc[n], 0, 0, 0);
            dacc[n] = __builtin_amdgcn_mfma_f32_16x16x32_bf16(ah1, bl1, dacc[n], 0, 0, 0);
        }
        __syncthreads();
    }

    // per-lane argmin over this lane's 16 codes, for 4 C-rows (regs)
    float best[4] = {3.4e38f, 3.4e38f, 3.4e38f, 3.4e38f};
    int   bidx[4] = {0, 0, 0, 0};
    #pragma unroll
    for (int n = 0; n < 16; ++n) {
        int code = n * 16 + tm;
        float ccv = ccs[code];
        #pragma unroll
        for (int r = 0; r < 4; ++r) {
            float d = ccv - 2.f * dacc[n][r];
            if (d < best[r]) { best[r] = d; bidx[r] = code; }   // codes increase: '<' keeps lowest idx
        }
    }
    // butterfly min+idx across the 16-lane col group (masks 1,2,4,8 keep lane>>4)
    #pragma unroll
    for (int r = 0; r < 4; ++r) {
        #pragma unroll
        for (int m = 1; m < 16; m <<= 1) {
            float ob = __shfl_xor(best[r], m, 64);
            int   oi = __shfl_xor(bidx[r], m, 64);
            if (ob < best[r] || (ob == best[r] && oi < bidx[r])) { best[r] = ob; bidx[r] = oi; }
        }
        if (tm == 0) {
            int row  = q * 4 + r;
            int grow = r0 + w * 16 + row;
            widx[w * 16 + row] = bidx[r];
            out_idx[grow] = (float)bidx[r];
            idxi[grow]    = bidx[r];
        }
    }
    __syncthreads();

    // copy winning codebook rows (exact fp32) + SSD
    float ssd = 0.f;
    for (int r = 0; r < 64; ++r) {
        int win = widx[r];
        float4 qv = ((const float4*)(cb + (long)win * ND))[tid];
        ((float4*)(out_q + (long)(r0 + r) * ND))[tid] = qv;
        float4 fv = ((const float4*)(feat + (long)(r0 + r) * ND))[tid];
        float dx = fv.x - qv.x, dy = fv.y - qv.y, dz = fv.z - qv.z, dw = fv.w - qv.w;
        ssd += dx * dx + dy * dy + dz * dz + dw * dw;
    }
    #pragma unroll
    for (int m = 1; m < 64; m <<= 1) ssd += __shfl_xor(ssd, m, 64);
    if (lane == 0) sp[w] = ssd;
    __syncthreads();
    if (tid == 0) atomicAdd(&acc[33], sp[0] + sp[1] + sp[2] + sp[3]);
}

// ---------------- fp32 tiled GEMM: C[M,N] = A[M,K] * W[N,K]^T + bias[N] ----------------
// (only used for the small GIcb = cb @ W_ih^T)
__global__ __launch_bounds__(256) void gemm_nt(
    const float* __restrict__ A, const float* __restrict__ W,
    const float* __restrict__ bias, float* __restrict__ C, int N, int K)
{
    __shared__ float As[16][132];
    __shared__ float Bs[16][132];
    int tid = threadIdx.x;
    int m0 = blockIdx.y * 128;
    int n0 = blockIdx.x * 128;
    int tx = tid & 15, ty = tid >> 4;

    float accum[8][8];
    #pragma unroll
    for (int i = 0; i < 8; ++i)
        #pragma unroll
        for (int j = 0; j < 8; ++j) accum[i][j] = 0.f;

    for (int k0 = 0; k0 < K; k0 += 16) {
        #pragma unroll
        for (int i = 0; i < 2; ++i) {
            int f   = tid + i * 256;
            int row = f >> 2;
            int kq  = f & 3;
            float4 a = *(const float4*)(A + (long)(m0 + row) * K + k0 + kq * 4);
            As[kq * 4 + 0][row] = a.x; As[kq * 4 + 1][row] = a.y;
            As[kq * 4 + 2][row] = a.z; As[kq * 4 + 3][row] = a.w;
            float4 b = *(const float4*)(W + (long)(n0 + row) * K + k0 + kq * 4);
            Bs[kq * 4 + 0][row] = b.x; Bs[kq * 4 + 1][row] = b.y;
            Bs[kq * 4 + 2][row] = b.z; Bs[kq * 4 + 3][row] = b.w;
        }
        __syncthreads();
        #pragma unroll
        for (int kk = 0; kk < 16; ++kk) {
            float4 a01 = *(const float4*)&As[kk][ty * 8];
            float4 a23 = *(const float4*)&As[kk][ty * 8 + 4];
            float4 b01 = *(const float4*)&Bs[kk][tx * 8];
            float4 b23 = *(const float4*)&Bs[kk][tx * 8 + 4];
            float av[8] = {a01.x, a01.y, a01.z, a01.w, a23.x, a23.y, a23.z, a23.w};
            float bv[8] = {b01.x, b01.y, b01.z, b01.w, b23.x, b23.y, b23.z, b23.w};
            #pragma unroll
            for (int i = 0; i < 8; ++i)
                #pragma unroll
                for (int j = 0; j < 8; ++j) accum[i][j] += av[i] * bv[j];
        }
        __syncthreads();
    }
    #pragma unroll
    for (int i = 0; i < 8; ++i) {
        float* crow = C + (long)(m0 + ty * 8 + i) * N + n0 + tx * 8;
        const float* brow = bias + n0 + tx * 8;
        float4 o0, o1;
        o0.x = accum[i][0] + brow[0]; o0.y = accum[i][1] + brow[1];
        o0.z = accum[i][2] + brow[2]; o0.w = accum[i][3] + brow[3];
        o1.x = accum[i][4] + brow[4]; o1.y = accum[i][5] + brow[5];
        o1.z = accum[i][6] + brow[6]; o1.w = accum[i][7] + brow[7];
        *(float4*)(crow)     = o0;
        *(float4*)(crow + 4) = o1;
    }
}

// ---------------- persistent GRU v8: ctx store moved OFF the critical path ----------------
// 2 groups of 16 batches; 128 col-blocks each owning 8 j-cols. tile0 = [g0|g1],
// tile1 = [g2|W_proj] (ctx fused). v8: the ctx fp32 store now happens AFTER the
// slot publish — it has no consumer until cp_kernel, so it no longer sits inside
// the pre-publish vmcnt(0) drain that every block's step latency chains on.
__global__ __launch_bounds__(256, 1) void gru_persist(
    float* ctxp,
    const unsigned short* __restrict__ Whi, const unsigned short* __restrict__ Wlo,
    const unsigned short* __restrict__ Phi, const unsigned short* __restrict__ Plo,
    const float* __restrict__ GIcb, const int* __restrict__ idxi,
    const float* __restrict__ b_hh, const float* __restrict__ b_proj,
    unsigned short* hA,   // [2 buf][2 grp][hi/lo][32 kk][64 lane][8] ushorts
    int* slots)           // [2 grp][128] per-block completed-step epochs
{
    __shared__ unsigned short whi0[32][16][32];   // 32 KB: tile0 (cols 0-7=g0, 8-15=g1)
    __shared__ unsigned short whi1[32][16][32];   // 32 KB: tile1 (cols 0-7=g2, 8-15=W_proj)
    __shared__ float red[4][64][9];               // 9.2 KB: k-split partials

    int tid  = threadIdx.x;
    int lane = tid & 63;
    int w    = tid >> 6;
    int bid  = blockIdx.x;
    int grp  = bid >> 7;
    int bidp = bid & 127;
    int jb   = bidp * 8;
    int q    = lane >> 4;
    int tc   = lane & 15;

    // ---- stage W-hi slices into LDS (32 virtual rows x 1024) ----
    for (int it = 0; it < 16; ++it) {
        int u8  = it * 256 + tid;
        int r32 = u8 >> 7;
        int k   = (u8 & 127) * 8;
        int g = r32 >> 3, r = r32 & 7;
        const unsigned short* src = (g < 3)
            ? (Whi + (long)((g << 10) + jb + r) * 1024 + k)
            : (Phi + (long)(jb + r) * 1024 + k);
        s16x8 v = *(const s16x8*)src;
        if (g == 0)      *(s16x8*)&whi0[k >> 5][r][k & 31]     = v;
        else if (g == 1) *(s16x8*)&whi0[k >> 5][8 + r][k & 31] = v;
        else if (g == 2) *(s16x8*)&whi1[k >> 5][r][k & 31]     = v;
        else             *(s16x8*)&whi1[k >> 5][8 + r][k & 31] = v;
    }

    // ---- pin W-lo fragments in registers ----
    s16x8 wlof[8][2];
    #pragma unroll
    for (int kl = 0; kl < 8; ++kl) {
        int kg = w * 256 + kl * 32 + q * 8;
        int row0 = (tc < 8) ? (jb + tc) : (1024 + jb + (tc - 8));
        wlof[kl][0] = *(const s16x8*)(Wlo + (long)row0 * 1024 + kg);
        wlof[kl][1] = (tc < 8)
            ? *(const s16x8*)(Wlo + (long)(2048 + jb + tc) * 1024 + kg)
            : *(const s16x8*)(Plo + (long)(jb + (tc - 8)) * 1024 + kg);
    }
    __syncthreads();

    // ---- epilogue constants ----
    int ebg = (tid >> 3) & 15;
    int eb  = grp * 16 + ebg;
    int ejl = tid & 7;
    int jg  = jb + ejl;
    int eq  = ebg >> 2, eer = ebg & 3;
    float bhr = b_hh[jg], bhz = b_hh[ND + jg], bhn = b_hh[2 * ND + jg];
    float bpj = b_proj[jg];
    int akk = jg >> 5, aqp = (jg >> 3) & 3, aj8 = jg & 7;
    int alane = aqp * 16 + ebg;
    int awoff = (akk * 64 + alane) * 8 + aj8;
    float hp = 0.f;

    #pragma unroll 1
    for (int t = 0; t <= NT; ++t) {
        int tcl = (t < NT) ? t : (NT - 1);
        int cidx = idxi[eb * NT + tcl];
        const float* gib = GIcb + (long)cidx * NG;
        float gi0 = gib[jg], gi1 = gib[ND + jg], gi2 = gib[2 * ND + jg];

        if (t > 0) {
            bool ok;
            do {
                int s1 = __hip_atomic_load(slots + grp * 128 + lane,      __ATOMIC_RELAXED, __HIP_MEMORY_SCOPE_AGENT);
                int s2 = __hip_atomic_load(slots + grp * 128 + 64 + lane, __ATOMIC_RELAXED, __HIP_MEMORY_SCOPE_AGENT);
                ok = (__all((s1 >= t) && (s2 >= t)) != 0);
                if (!ok) __builtin_amdgcn_s_sleep(1);
            } while (!ok);
        }

        const unsigned short* rHi = hA + ((unsigned)((t & 1) * 2 + grp) * 2 + 0) * 16384;
        const unsigned short* rLo = rHi + 16384;
        unsigned short* wHi = hA + ((unsigned)((((t + 1) & 1)) * 2 + grp) * 2 + 0) * 16384;
        unsigned short* wLo = wHi + 16384;

        s16x8 Ah[8], Al[8];
        #pragma unroll
        for (int kl = 0; kl < 8; ++kl) {
            int kk = w * 8 + kl;
            Ah[kl] = llc_load16(rHi + kk * 512 + lane * 8);
            Al[kl] = llc_load16(rLo + kk * 512 + lane * 8);
        }
        asm volatile("s_waitcnt vmcnt(0)" ::: "memory");

        f32x4 acc0 = (f32x4){0.f, 0.f, 0.f, 0.f};
        f32x4 acc1 = (f32x4){0.f, 0.f, 0.f, 0.f};

        #pragma unroll
        for (int kl = 0; kl < 8; ++kl) {
            int kk = w * 8 + kl;
            s16x8 bh0 = *(const s16x8*)&whi0[kk][tc][q * 8];
            s16x8 bh1 = *(const s16x8*)&whi1[kk][tc][q * 8];
            acc0 = __builtin_amdgcn_mfma_f32_16x16x32_bf16(Ah[kl], bh0, acc0, 0, 0, 0);
            acc1 = __builtin_amdgcn_mfma_f32_16x16x32_bf16(Ah[kl], bh1, acc1, 0, 0, 0);
            acc0 = __builtin_amdgcn_mfma_f32_16x16x32_bf16(Al[kl], bh0, acc0, 0, 0, 0);
            acc1 = __builtin_amdgcn_mfma_f32_16x16x32_bf16(Al[kl], bh1, acc1, 0, 0, 0);
            acc0 = __builtin_amdgcn_mfma_f32_16x16x32_bf16(Ah[kl], wlof[kl][0], acc0, 0, 0, 0);
            acc1 = __builtin_amdgcn_mfma_f32_16x16x32_bf16(Ah[kl], wlof[kl][1], acc1, 0, 0, 0);
        }

        #pragma unroll
        for (int r = 0; r < 4; ++r) {
            red[w][lane][r]     = acc0[r];
            red[w][lane][4 + r] = acc1[r];
        }
        __syncthreads();

        float g0 = 0.f, g1 = 0.f, g2 = 0.f, cx = 0.f;
        #pragma unroll
        for (int ww = 0; ww < 4; ++ww) {
            g0 += red[ww][eq * 16 + ejl][eer];
            g1 += red[ww][eq * 16 + 8 + ejl][eer];
            g2 += red[ww][eq * 16 + ejl][4 + eer];
            cx += red[ww][eq * 16 + 8 + ejl][4 + eer];
        }
        if (tid < 128 && t < NT) {
            float xr = gi0 + g0 + bhr;
            float xz = gi1 + g1 + bhz;
            float rg = 1.f / (1.f + __expf(-xr));
            float zg = 1.f / (1.f + __expf(-xz));
            float narg = gi2 + rg * (g2 + bhn);
            float e2 = __expf(2.f * narg);
            float ng = 1.f - 2.f / (e2 + 1.f);
            float hnew = (1.f - zg) * ng + zg * hp;
            hp = hnew;
            unsigned short hh = f32_to_bf16(hnew);
            unsigned short hl = f32_to_bf16(hnew - bf16_to_f32(hh));
            llc_store2(wHi + awoff, (unsigned int)hh);
            llc_store2(wLo + awoff, (unsigned int)hl);
        }
        if (t < NT) {
            asm volatile("s_waitcnt vmcnt(0)" ::: "memory");   // h stores drained to LLC
            __syncthreads();                                   // whole block done
            if (tid == 0)
                llc_store4(slots + grp * 128 + bidp, t + 1);   // relaxed LLC publish
        }
        // ctx row t-1 (A-frags this step were h(t-1)): no consumer until cp_kernel,
        // so store AFTER the publish — off the inter-block critical path.
        if (tid < 128 && t > 0) {
            ctxp[((long)eb * NT + (t - 1)) * ND + jg] = cx + bpj;
        }
    }
}

// ---------------- CPC loss: one block per (k,l) ----------------
__global__ __launch_bounds__(256) void cp_kernel(
    const float* __restrict__ feat, const float* __restrict__ ctx,
    const int* __restrict__ perm, float* __restrict__ acc)
{
    __shared__ float cx[32][256];
    __shared__ float red2[4];

    int tid = threadIdx.x;
    int bk = blockIdx.x;
    int kk, l;
    if (bk < 511)       { kk = 1; l = bk; }
    else if (bk < 1021) { kk = 2; l = bk - 511; }
    else                { kk = 3; l = bk - 1021; }

    float dacc[5] = {0.f, 0.f, 0.f, 0.f, 0.f};
    for (int c = 0; c < 4; ++c) {
        for (int i = 0; i < 8; ++i) {
            int g = i * 256 + tid;
            int b = g >> 6, kq = g & 63;
            *(float4*)&cx[b][kq * 4] =
                *(const float4*)(ctx + (long)(b * NT + l) * ND + c * 256 + kq * 4);
        }
        __syncthreads();
        for (int oi = 0; oi < 5; ++oi) {
            int o = tid + oi * 256;
            if (o < 1056) {
                int b = o / 33, ii = o % 33;
                const float* frow = (ii < 32)
                    ? (feat + (long)(perm[(kk - 1) * 32 + ii] * NT + l) * ND)
                    : (feat + (long)(b * NT + l + kk) * ND);
                const float4* fp4 = (const float4*)(frow + c * 256);
                const float4* cp4 = (const float4*)&cx[b][0];
                float s = 0.f;
                for (int k4 = 0; k4 < 64; ++k4) {
                    float4 cf = cp4[k4];
                    float4 ff = fp4[k4];
                    s += cf.x * ff.x + cf.y * ff.y + cf.z * ff.z + cf.w * ff.w;
                }
                dacc[oi] += s;
            }
        }
        __syncthreads();
    }

    float nsum = 0.f;
    for (int oi = 0; oi < 5; ++oi) {
        int o = tid + oi * 256;
        if (o < 1056) {
            int b = o / 33, ii = o % 33;
            float x = dacc[oi];
            if (ii < 32) {
                float sn = 1.f / (1.f + expf(x));
                nsum += -logf(sn + 1e-8f);
            } else {
                float sp = 1.f / (1.f + expf(-x));
                atomicAdd(&acc[b], -logf(sp + 1e-8f));
            }
        }
    }
    #pragma unroll
    for (int m = 1; m < 64; m <<= 1) nsum += __shfl_xor(nsum, m, 64);
    if ((tid & 63) == 0) red2[tid >> 6] = nsum;
    __syncthreads();
    if (tid == 0) atomicAdd(&acc[32], red2[0] + red2[1] + red2[2] + red2[3]);
}

// ---------------- finalize ----------------
__global__ void finalize_kernel(const float* __restrict__ acc, float* __restrict__ out) {
    int b = threadIdx.x;
    if (b < 32) {
        float cp = (acc[b] + 0.25f * acc[32] * (1.0f / 1024.0f)) * (1.0f / 1527.0f);
        float vq = 1.25f * acc[33] * (1.0f / 16777216.0f);
        out[b] = cp + vq;
    }
}

// ---------------- launch ----------------
extern "C" void kernel_launch(void* const* d_in, const int* in_sizes, int n_in,
                              void* d_out, int out_size, void* d_ws, size_t ws_size,
                              hipStream_t stream)
{
    const float* feat   = (const float*)d_in[0];
    const float* cb     = (const float*)d_in[1];
    const float* W_ih   = (const float*)d_in[2];
    const float* W_hh   = (const float*)d_in[3];
    const float* b_ih   = (const float*)d_in[4];
    const float* b_hh   = (const float*)d_in[5];
    const float* W_proj = (const float*)d_in[6];
    const float* b_proj = (const float*)d_in[7];
    const int*   nperm  = (const int*)d_in[8];

    float* outq    = (float*)d_out;
    float* outidx  = outq + 16777216;
    float* outloss = outq + 16793600;

    char* ws = (char*)d_ws;
    float*          ctx  = (float*)(ws);                       //  67,108,864 B
    unsigned short* Whi  = (unsigned short*)(ws + 67108864);   //   6,291,456 B
    unsigned short* Wlo  = (unsigned short*)(ws + 73400320);   //   6,291,456 B
    unsigned short* Phi  = (unsigned short*)(ws + 79691776);   //   2,097,152 B
    unsigned short* Plo  = (unsigned short*)(ws + 81788928);   //   2,097,152 B
    float*          GIcb = (float*)(ws + 83886080);            //   3,145,728 B
    int*            idxi = (int*)(ws + 87031808);              //      65,536 B
    float*          acc  = (float*)(ws + 87097344);            //  256 B acc
    int*            slots= (int*)(ws + 87097600);              //  1024 B barrier slots
    unsigned short* hA   = (unsigned short*)(ws + 87098624);   //  262,144 B h frag bufs
    unsigned short* cbHi = (unsigned short*)(ws + 87360768);   //     524,288 B
    unsigned short* cbLo = (unsigned short*)(ws + 87885056);   //     524,288 B
    float*          ccg  = (float*)(ws + 88409344);            //       1,024 B
    // feat bf16 hi/lo OVERLAYS ctx: used only before gru_persist writes ctx.
    unsigned short* featHi = (unsigned short*)(ws);            //  33,554,432 B
    unsigned short* featLo = (unsigned short*)(ws + 33554432); //  33,554,432 B

    // zero acc (256) + slots (1024) + hA buffer 0 hi+lo both groups (131072)
    hipMemsetAsync(acc, 0, 256 + 1024 + 131072, stream);
    prep_w<<<12288, 256, 0, stream>>>(W_hh, Whi, Wlo);
    prep_w<<<4096, 256, 0, stream>>>(W_proj, Phi, Plo);
    prep_split<<<8192, 256, 0, stream>>>(feat, featHi, featLo);
    prep_split<<<128, 256, 0, stream>>>(cb, cbHi, cbLo);
    cc_kernel<<<1, 256, 0, stream>>>(cb, ccg);
    quantize_mfma<<<256, 256, 0, stream>>>(feat, cb, featHi, featLo, cbHi, cbLo, ccg,
                                           outq, outidx, idxi, acc);
    // GIcb = codebook @ W_ih^T + b_ih  (256x3072, K=1024)
    gemm_nt<<<dim3(24, 2), 256, 0, stream>>>(cb, W_ih, b_ih, GIcb, NG, ND);
    // persistent GRU: 513 in-kernel steps, ctx fused (tile1 cols 8-15 = W_proj)
    gru_persist<<<GRU_BLOCKS, 256, 0, stream>>>(ctx, Whi, Wlo, Phi, Plo, GIcb, idxi,
                                                b_hh, b_proj, hA, slots);
    cp_kernel<<<1530, 256, 0, stream>>>(feat, ctx, nperm, acc);
    finalize_kernel<<<1, 64, 0, stream>>>(acc, outloss);
}

// Round 5
// 2272.615 us; speedup vs baseline: 2.8038x; 1.2809x over previous
//
#include <hip/hip_runtime.h>
#include <stdint.h>

// Problem constants (fixed by reference): B=32, T=512, d=1024, Kcb=256
#define NB    32
#define NT    512
#define ND    1024
#define NG    3072      // 3*d
#define NROW  16384     // B*T
#define KCB   256
#define GRU_BLOCKS 256  // 2 independent batch-groups x 128 col-blocks

typedef float  f32x4 __attribute__((ext_vector_type(4)));
typedef short  s16x8 __attribute__((ext_vector_type(8)));

// ---------------- bf16 helpers (hi/lo split precision) ----------------
__device__ __forceinline__ unsigned short f32_to_bf16(float x) {
    union { float f; unsigned int u; } v; v.f = x;
    unsigned int u = v.u;
    return (unsigned short)((u + 0x7FFFu + ((u >> 16) & 1u)) >> 16);
}
__device__ __forceinline__ float bf16_to_f32(unsigned short h) {
    union { float f; unsigned int u; } v; v.u = ((unsigned int)h) << 16; return v.f;
}

// LLC-coherent (L1/L2-bypassing) 16B load / 2B store — cross-XCD fresh without fences.
__device__ __forceinline__ s16x8 llc_load16(const unsigned short* p) {
    s16x8 r;
    asm volatile("global_load_dwordx4 %0, %1, off sc0 sc1" : "=v"(r) : "v"(p) : "memory");
    return r;
}
__device__ __forceinline__ void llc_store2(unsigned short* p, unsigned int v) {
    asm volatile("global_store_short %0, %1, off sc0 sc1" :: "v"(p), "v"(v) : "memory");
}
// Relaxed LLC-level 4B store: publishes the step slot WITHOUT the agent-release
// buffer_wbl2 (full L2 writeback + drain) that RELEASE/AGENT atomics emit.
__device__ __forceinline__ void llc_store4(int* p, int v) {
    asm volatile("global_store_dword %0, %1, off sc0 sc1" :: "v"(p), "v"(v) : "memory");
}

// ---------------- W -> bf16 hi/lo split (grid sized = elems/256) ----------------
__global__ __launch_bounds__(256) void prep_w(const float* __restrict__ W,
                                              unsigned short* __restrict__ Whi,
                                              unsigned short* __restrict__ Wlo) {
    int i = blockIdx.x * 256 + threadIdx.x;
    float w = W[i];
    unsigned short hi = f32_to_bf16(w);
    float rem = w - bf16_to_f32(hi);
    Whi[i] = hi;
    Wlo[i] = f32_to_bf16(rem);
}

// ---------------- vectorized hi/lo split: 8 elems/thread (grid = elems/2048) ----------------
__global__ __launch_bounds__(256) void prep_split(const float* __restrict__ X,
                                                  unsigned short* __restrict__ Hi,
                                                  unsigned short* __restrict__ Lo) {
    long i8 = ((long)blockIdx.x * 256 + threadIdx.x) * 8;
    float4 a = *(const float4*)(X + i8);
    float4 b = *(const float4*)(X + i8 + 4);
    float xs[8] = {a.x, a.y, a.z, a.w, b.x, b.y, b.z, b.w};
    s16x8 hi, lo;
    #pragma unroll
    for (int j = 0; j < 8; ++j) {
        unsigned short h = f32_to_bf16(xs[j]);
        hi[j] = (short)h;
        lo[j] = (short)f32_to_bf16(xs[j] - bf16_to_f32(h));
    }
    *(s16x8*)(Hi + i8) = hi;
    *(s16x8*)(Lo + i8) = lo;
}

// ---------------- ||c||^2 in fp64, once (1 block, 256 threads) ----------------
__global__ __launch_bounds__(256) void cc_kernel(const float* __restrict__ cb,
                                                 float* __restrict__ ccg) {
    int c = threadIdx.x;
    const float4* row = (const float4*)(cb + (long)c * ND);
    double s = 0.0;
    for (int i = 0; i < 256; ++i) {
        float4 v = row[i];
        s += (double)v.x * (double)v.x + (double)v.y * (double)v.y
           + (double)v.z * (double)v.z + (double)v.w * (double)v.w;
    }
    ccg[c] = (float)s;
}

// ---------------- MFMA quantize v2: in-register feat hi/lo split ----------------
// 256 blocks x 64 rows. argmin over c of (||c||^2 - 2 f.c), bf16 hi/lo 3-pass dots.
// v2: feat A-fragments are loaded fp32 and split to bf16 hi/lo IN-KERNEL —
// deletes the 128MB-traffic prep_split(feat) dispatch and the fHi/fLo arrays.
__global__ __launch_bounds__(256, 1) void quantize_mfma(
    const float* __restrict__ feat, const float* __restrict__ cb,
    const unsigned short* __restrict__ cHi, const unsigned short* __restrict__ cLo,
    const float* __restrict__ ccg,
    float* __restrict__ out_q, float* __restrict__ out_idx,
    int* __restrict__ idxi, float* __restrict__ acc)
{
    __shared__ unsigned short cbsH[256][64];   // 32 KB, k XOR-swizzled
    __shared__ unsigned short cbsL[256][64];   // 32 KB
    __shared__ float ccs[256];
    __shared__ int   widx[64];
    __shared__ float sp[4];

    int tid  = threadIdx.x;
    int lane = tid & 63;
    int w    = tid >> 6;
    int r0   = blockIdx.x * 64;
    int tm   = lane & 15;          // M-row / N-col within tile
    int q    = lane >> 4;          // k sub-chunk

    ccs[tid] = ccg[tid];

    f32x4 dacc[16];
    #pragma unroll
    for (int n = 0; n < 16; ++n) dacc[n] = (f32x4){0.f, 0.f, 0.f, 0.f};

    const long arow = (long)(r0 + w * 16 + tm) * ND;

    for (int kc = 0; kc < 16; ++kc) {
        int k0 = kc * 64;
        // stage codebook chunk [256 codes][64 k] hi+lo, XOR-swizzled in k
        #pragma unroll
        for (int it = 0; it < 8; ++it) {
            int u    = it * 256 + tid;        // 0..2047
            int code = u >> 3;
            int j8   = u & 7;
            int ksw  = (j8 * 8) ^ ((code & 7) << 3);
            *(s16x8*)&cbsH[code][ksw] = *(const s16x8*)(cHi + (long)code * ND + k0 + j8 * 8);
            *(s16x8*)&cbsL[code][ksw] = *(const s16x8*)(cLo + (long)code * ND + k0 + j8 * 8);
        }
        // A-frags: fp32 loads + in-register hi/lo split
        float4 a0 = *(const float4*)(feat + arow + k0 + q * 8);
        float4 a1 = *(const float4*)(feat + arow + k0 + q * 8 + 4);
        float4 a2 = *(const float4*)(feat + arow + k0 + 32 + q * 8);
        float4 a3 = *(const float4*)(feat + arow + k0 + 32 + q * 8 + 4);
        s16x8 ah0, al0, ah1, al1;
        {
            float xs[8] = {a0.x, a0.y, a0.z, a0.w, a1.x, a1.y, a1.z, a1.w};
            #pragma unroll
            for (int j = 0; j < 8; ++j) {
                unsigned short h = f32_to_bf16(xs[j]);
                ah0[j] = (short)h;
                al0[j] = (short)f32_to_bf16(xs[j] - bf16_to_f32(h));
            }
            float ys[8] = {a2.x, a2.y, a2.z, a2.w, a3.x, a3.y, a3.z, a3.w};
            #pragma unroll
            for (int j = 0; j < 8; ++j) {
                unsigned short h = f32_to_bf16(ys[j]);
                ah1[j] = (short)h;
                al1[j] = (short)f32_to_bf16(ys[j] - bf16_to_f32(h));
            }
        }
        __syncthreads();
        int ksw0 = (q * 8) ^ ((tm & 7) << 3);
        int ksw1 = (32 + q * 8) ^ ((tm & 7) << 3);
        #pragma unroll
        for (int n = 0; n < 16; ++n) {
            s16x8 bh0 = *(const s16x8*)&cbsH[n * 16 + tm][ksw0];
            s16x8 bh1 = *(const s16x8*)&cbsH[n * 16 + tm][ksw1];
            s16x8 bl0 = *(const s16x8*)&cbsL[n * 16 + tm][ksw0];
            s16x8 bl1 = *(const s16x8*)&cbsL[n * 16 + tm][ksw1];
            dacc[n] = __builtin_amdgcn_mfma_f32_16x16x32_bf16(ah0, bh0, dacc[n], 0, 0, 0);
            dacc[n] = __builtin_amdgcn_mfma_f32_16x16x32_bf16(al0, bh0, dacc[n], 0, 0, 0);
            dacc[n] = __builtin_amdgcn_mfma_f32_16x16x32_bf16(ah0, bl0, dacc[n], 0, 0, 0);
            dacc[n] = __builtin_amdgcn_mfma_f32_16x16x32_bf16(ah1, bh1, dacc[n], 0, 0, 0);
            dacc[n] = __builtin_amdgcn_mfma_f32_16x16x32_bf16(al1, bh1, dacc[n], 0, 0, 0);
            dacc[n] = __builtin_amdgcn_mfma_f32_16x16x32_bf16(ah1, bl1, dacc[n], 0, 0, 0);
        }
        __syncthreads();
    }

    // per-lane argmin over this lane's 16 codes, for 4 C-rows
    float best[4] = {3.4e38f, 3.4e38f, 3.4e38f, 3.4e38f};
    int   bidx[4] = {0, 0, 0, 0};
    #pragma unroll
    for (int n = 0; n < 16; ++n) {
        int code = n * 16 + tm;
        float ccv = ccs[code];
        #pragma unroll
        for (int r = 0; r < 4; ++r) {
            float d = ccv - 2.f * dacc[n][r];
            if (d < best[r]) { best[r] = d; bidx[r] = code; }
        }
    }
    #pragma unroll
    for (int r = 0; r < 4; ++r) {
        #pragma unroll
        for (int m = 1; m < 16; m <<= 1) {
            float ob = __shfl_xor(best[r], m, 64);
            int   oi = __shfl_xor(bidx[r], m, 64);
            if (ob < best[r] || (ob == best[r] && oi < bidx[r])) { best[r] = ob; bidx[r] = oi; }
        }
        if (tm == 0) {
            int row  = q * 4 + r;
            int grow = r0 + w * 16 + row;
            widx[w * 16 + row] = bidx[r];
            out_idx[grow] = (float)bidx[r];
            idxi[grow]    = bidx[r];
        }
    }
    __syncthreads();

    // copy winning codebook rows (exact fp32) + SSD
    float ssd = 0.f;
    for (int r = 0; r < 64; ++r) {
        int win = widx[r];
        float4 qv = ((const float4*)(cb + (long)win * ND))[tid];
        ((float4*)(out_q + (long)(r0 + r) * ND))[tid] = qv;
        float4 fv = ((const float4*)(feat + (long)(r0 + r) * ND))[tid];
        float dx = fv.x - qv.x, dy = fv.y - qv.y, dz = fv.z - qv.z, dw = fv.w - qv.w;
        ssd += dx * dx + dy * dy + dz * dz + dw * dw;
    }
    #pragma unroll
    for (int m = 1; m < 64; m <<= 1) ssd += __shfl_xor(ssd, m, 64);
    if (lane == 0) sp[w] = ssd;
    __syncthreads();
    if (tid == 0) atomicAdd(&acc[33], sp[0] + sp[1] + sp[2] + sp[3]);
}

// ---------------- fp32 tiled GEMM: C[M,N] = A[M,K] * W[N,K]^T + bias[N] ----------------
// (only used for the small GIcb = cb @ W_ih^T)
__global__ __launch_bounds__(256) void gemm_nt(
    const float* __restrict__ A, const float* __restrict__ W,
    const float* __restrict__ bias, float* __restrict__ C, int N, int K)
{
    __shared__ float As[16][132];
    __shared__ float Bs[16][132];
    int tid = threadIdx.x;
    int m0 = blockIdx.y * 128;
    int n0 = blockIdx.x * 128;
    int tx = tid & 15, ty = tid >> 4;

    float accum[8][8];
    #pragma unroll
    for (int i = 0; i < 8; ++i)
        #pragma unroll
        for (int j = 0; j < 8; ++j) accum[i][j] = 0.f;

    for (int k0 = 0; k0 < K; k0 += 16) {
        #pragma unroll
        for (int i = 0; i < 2; ++i) {
            int f   = tid + i * 256;
            int row = f >> 2;
            int kq  = f & 3;
            float4 a = *(const float4*)(A + (long)(m0 + row) * K + k0 + kq * 4);
            As[kq * 4 + 0][row] = a.x; As[kq * 4 + 1][row] = a.y;
            As[kq * 4 + 2][row] = a.z; As[kq * 4 + 3][row] = a.w;
            float4 b = *(const float4*)(W + (long)(n0 + row) * K + k0 + kq * 4);
            Bs[kq * 4 + 0][row] = b.x; Bs[kq * 4 + 1][row] = b.y;
            Bs[kq * 4 + 2][row] = b.z; Bs[kq * 4 + 3][row] = b.w;
        }
        __syncthreads();
        #pragma unroll
        for (int kk = 0; kk < 16; ++kk) {
            float4 a01 = *(const float4*)&As[kk][ty * 8];
            float4 a23 = *(const float4*)&As[kk][ty * 8 + 4];
            float4 b01 = *(const float4*)&Bs[kk][tx * 8];
            float4 b23 = *(const float4*)&Bs[kk][tx * 8 + 4];
            float av[8] = {a01.x, a01.y, a01.z, a01.w, a23.x, a23.y, a23.z, a23.w};
            float bv[8] = {b01.x, b01.y, b01.z, b01.w, b23.x, b23.y, b23.z, b23.w};
            #pragma unroll
            for (int i = 0; i < 8; ++i)
                #pragma unroll
                for (int j = 0; j < 8; ++j) accum[i][j] += av[i] * bv[j];
        }
        __syncthreads();
    }
    #pragma unroll
    for (int i = 0; i < 8; ++i) {
        float* crow = C + (long)(m0 + ty * 8 + i) * N + n0 + tx * 8;
        const float* brow = bias + n0 + tx * 8;
        float4 o0, o1;
        o0.x = accum[i][0] + brow[0]; o0.y = accum[i][1] + brow[1];
        o0.z = accum[i][2] + brow[2]; o0.w = accum[i][3] + brow[3];
        o1.x = accum[i][4] + brow[4]; o1.y = accum[i][5] + brow[5];
        o1.z = accum[i][6] + brow[6]; o1.w = accum[i][7] + brow[7];
        *(float4*)(crow)     = o0;
        *(float4*)(crow + 4) = o1;
    }
}

// ---------------- persistent GRU v9: per-wave quarter-barrier ----------------
// 2 groups of 16 batches; 128 col-blocks each owning 8 j-cols. tile0=[g0|g1],
// tile1=[g2|W_proj] (ctx fused, stored after publish). v9: wave w consumes only
// k in [256w, 256w+256) = producer blocks [32w, 32w+32), so it polls ONLY those
// 32 slots (1 load not 2) and proceeds straight to its A-loads+MFMA. Producer
// jitter in one quarter overlaps other waves' compute on the same CU.
__global__ __launch_bounds__(256, 1) void gru_persist(
    float* ctxp,
    const unsigned short* __restrict__ Whi, const unsigned short* __restrict__ Wlo,
    const unsigned short* __restrict__ Phi, const unsigned short* __restrict__ Plo,
    const float* __restrict__ GIcb, const int* __restrict__ idxi,
    const float* __restrict__ b_hh, const float* __restrict__ b_proj,
    unsigned short* hA,   // [2 buf][2 grp][hi/lo][32 kk][64 lane][8] ushorts
    int* slots)           // [2 grp][128] per-block completed-step epochs
{
    __shared__ unsigned short whi0[32][16][32];   // 32 KB
    __shared__ unsigned short whi1[32][16][32];   // 32 KB
    __shared__ float red[4][64][9];               // 9.2 KB

    int tid  = threadIdx.x;
    int lane = tid & 63;
    int w    = tid >> 6;
    int bid  = blockIdx.x;
    int grp  = bid >> 7;
    int bidp = bid & 127;
    int jb   = bidp * 8;
    int q    = lane >> 4;
    int tc   = lane & 15;

    // ---- stage W-hi slices into LDS (32 virtual rows x 1024) ----
    for (int it = 0; it < 16; ++it) {
        int u8  = it * 256 + tid;
        int r32 = u8 >> 7;
        int k   = (u8 & 127) * 8;
        int g = r32 >> 3, r = r32 & 7;
        const unsigned short* src = (g < 3)
            ? (Whi + (long)((g << 10) + jb + r) * 1024 + k)
            : (Phi + (long)(jb + r) * 1024 + k);
        s16x8 v = *(const s16x8*)src;
        if (g == 0)      *(s16x8*)&whi0[k >> 5][r][k & 31]     = v;
        else if (g == 1) *(s16x8*)&whi0[k >> 5][8 + r][k & 31] = v;
        else if (g == 2) *(s16x8*)&whi1[k >> 5][r][k & 31]     = v;
        else             *(s16x8*)&whi1[k >> 5][8 + r][k & 31] = v;
    }

    // ---- pin W-lo fragments in registers ----
    s16x8 wlof[8][2];
    #pragma unroll
    for (int kl = 0; kl < 8; ++kl) {
        int kg = w * 256 + kl * 32 + q * 8;
        int row0 = (tc < 8) ? (jb + tc) : (1024 + jb + (tc - 8));
        wlof[kl][0] = *(const s16x8*)(Wlo + (long)row0 * 1024 + kg);
        wlof[kl][1] = (tc < 8)
            ? *(const s16x8*)(Wlo + (long)(2048 + jb + tc) * 1024 + kg)
            : *(const s16x8*)(Plo + (long)(jb + (tc - 8)) * 1024 + kg);
    }
    __syncthreads();

    // ---- epilogue constants ----
    int ebg = (tid >> 3) & 15;
    int eb  = grp * 16 + ebg;
    int ejl = tid & 7;
    int jg  = jb + ejl;
    int eq  = ebg >> 2, eer = ebg & 3;
    float bhr = b_hh[jg], bhz = b_hh[ND + jg], bhn = b_hh[2 * ND + jg];
    float bpj = b_proj[jg];
    int akk = jg >> 5, aqp = (jg >> 3) & 3, aj8 = jg & 7;
    int alane = aqp * 16 + ebg;
    int awoff = (akk * 64 + alane) * 8 + aj8;
    float hp = 0.f;
    const int* mysl = slots + grp * 128 + w * 32;   // this wave's 32 producers

    #pragma unroll 1
    for (int t = 0; t <= NT; ++t) {
        int tcl = (t < NT) ? t : (NT - 1);
        int cidx = idxi[eb * NT + tcl];
        const float* gib = GIcb + (long)cidx * NG;
        float gi0 = gib[jg], gi1 = gib[ND + jg], gi2 = gib[2 * ND + jg];

        // per-wave quarter-barrier: only THIS wave's 32 producers must be done
        if (t > 0) {
            bool ok;
            do {
                int s1 = __hip_atomic_load(mysl + (lane & 31), __ATOMIC_RELAXED, __HIP_MEMORY_SCOPE_AGENT);
                ok = (__all(s1 >= t) != 0);
                if (!ok) __builtin_amdgcn_s_sleep(1);
            } while (!ok);
        }

        const unsigned short* rHi = hA + ((unsigned)((t & 1) * 2 + grp) * 2 + 0) * 16384;
        const unsigned short* rLo = rHi + 16384;
        unsigned short* wHi = hA + ((unsigned)((((t + 1) & 1)) * 2 + grp) * 2 + 0) * 16384;
        unsigned short* wLo = wHi + 16384;

        s16x8 Ah[8], Al[8];
        #pragma unroll
        for (int kl = 0; kl < 8; ++kl) {
            int kk = w * 8 + kl;
            Ah[kl] = llc_load16(rHi + kk * 512 + lane * 8);
            Al[kl] = llc_load16(rLo + kk * 512 + lane * 8);
        }
        asm volatile("s_waitcnt vmcnt(0)" ::: "memory");

        f32x4 acc0 = (f32x4){0.f, 0.f, 0.f, 0.f};
        f32x4 acc1 = (f32x4){0.f, 0.f, 0.f, 0.f};

        #pragma unroll
        for (int kl = 0; kl < 8; ++kl) {
            int kk = w * 8 + kl;
            s16x8 bh0 = *(const s16x8*)&whi0[kk][tc][q * 8];
            s16x8 bh1 = *(const s16x8*)&whi1[kk][tc][q * 8];
            acc0 = __builtin_amdgcn_mfma_f32_16x16x32_bf16(Ah[kl], bh0, acc0, 0, 0, 0);
            acc1 = __builtin_amdgcn_mfma_f32_16x16x32_bf16(Ah[kl], bh1, acc1, 0, 0, 0);
            acc0 = __builtin_amdgcn_mfma_f32_16x16x32_bf16(Al[kl], bh0, acc0, 0, 0, 0);
            acc1 = __builtin_amdgcn_mfma_f32_16x16x32_bf16(Al[kl], bh1, acc1, 0, 0, 0);
            acc0 = __builtin_amdgcn_mfma_f32_16x16x32_bf16(Ah[kl], wlof[kl][0], acc0, 0, 0, 0);
            acc1 = __builtin_amdgcn_mfma_f32_16x16x32_bf16(Ah[kl], wlof[kl][1], acc1, 0, 0, 0);
        }

        #pragma unroll
        for (int r = 0; r < 4; ++r) {
            red[w][lane][r]     = acc0[r];
            red[w][lane][4 + r] = acc1[r];
        }
        __syncthreads();

        float g0 = 0.f, g1 = 0.f, g2 = 0.f, cx = 0.f;
        #pragma unroll
        for (int ww = 0; ww < 4; ++ww) {
            g0 += red[ww][eq * 16 + ejl][eer];
            g1 += red[ww][eq * 16 + 8 + ejl][eer];
            g2 += red[ww][eq * 16 + ejl][4 + eer];
            cx += red[ww][eq * 16 + 8 + ejl][4 + eer];
        }
        if (tid < 128 && t < NT) {
            float xr = gi0 + g0 + bhr;
            float xz = gi1 + g1 + bhz;
            float rg = 1.f / (1.f + __expf(-xr));
            float zg = 1.f / (1.f + __expf(-xz));
            float narg = gi2 + rg * (g2 + bhn);
            float e2 = __expf(2.f * narg);
            float ng = 1.f - 2.f / (e2 + 1.f);
            float hnew = (1.f - zg) * ng + zg * hp;
            hp = hnew;
            unsigned short hh = f32_to_bf16(hnew);
            unsigned short hl = f32_to_bf16(hnew - bf16_to_f32(hh));
            llc_store2(wHi + awoff, (unsigned int)hh);
            llc_store2(wLo + awoff, (unsigned int)hl);
        }
        if (t < NT) {
            asm volatile("s_waitcnt vmcnt(0)" ::: "memory");   // h stores drained to LLC
            __syncthreads();                                   // whole block done
            if (tid == 0)
                llc_store4(slots + grp * 128 + bidp, t + 1);   // relaxed LLC publish
        }
        // ctx row t-1: stored after the publish — off the inter-block critical path.
        if (tid < 128 && t > 0) {
            ctxp[((long)eb * NT + (t - 1)) * ND + jg] = cx + bpj;
        }
    }
}

// ---------------- CPC neg loss via S-matrix: one block per l ----------------
// neg_logits[b,l,n] for ALL 3 k's are gathers of S[b,p] = ctx[b,l].feat[p,l]
// (neg rows are same-l feat rows, permuted). 511 blocks x 256 thr; each thread
// computes 4 S entries (b = tid>>3, n = (tid&7)*4 ..+4), then 12 gathered
// neg-loss terms per k. One atomic per block.
__global__ __launch_bounds__(256) void cp_s(
    const float* __restrict__ feat, const float* __restrict__ ctx,
    const int* __restrict__ perm, float* __restrict__ acc)
{
    __shared__ float S[32][33];
    __shared__ float red2[4];

    int t = threadIdx.x;
    int l = blockIdx.x;            // 0..510
    int b = t >> 3;
    int n0 = (t & 7) * 4;

    const float4* crow = (const float4*)(ctx + ((long)b * NT + l) * ND);
    const float4* f0 = (const float4*)(feat + ((long)(n0 + 0) * NT + l) * ND);
    const float4* f1 = (const float4*)(feat + ((long)(n0 + 1) * NT + l) * ND);
    const float4* f2 = (const float4*)(feat + ((long)(n0 + 2) * NT + l) * ND);
    const float4* f3 = (const float4*)(feat + ((long)(n0 + 3) * NT + l) * ND);
    float s0 = 0.f, s1 = 0.f, s2 = 0.f, s3 = 0.f;
    for (int j = 0; j < 256; ++j) {
        float4 cv = crow[j];
        float4 v0 = f0[j]; s0 += cv.x * v0.x + cv.y * v0.y + cv.z * v0.z + cv.w * v0.w;
        float4 v1 = f1[j]; s1 += cv.x * v1.x + cv.y * v1.y + cv.z * v1.z + cv.w * v1.w;
        float4 v2 = f2[j]; s2 += cv.x * v2.x + cv.y * v2.y + cv.z * v2.z + cv.w * v2.w;
        float4 v3 = f3[j]; s3 += cv.x * v3.x + cv.y * v3.y + cv.z * v3.z + cv.w * v3.w;
    }
    S[b][n0] = s0; S[b][n0 + 1] = s1; S[b][n0 + 2] = s2; S[b][n0 + 3] = s3;
    __syncthreads();

    float nsum = 0.f;
    #pragma unroll
    for (int k = 0; k < 3; ++k) {
        if (l < 511 - k) {           // valid iff l < T-(k+1)
            #pragma unroll
            for (int i = 0; i < 4; ++i) {
                int idx = t + i * 256;          // 0..1023
                int b2 = idx >> 5, n = idx & 31;
                int p = perm[k * 32 + n];
                float x = S[b2][p];
                float sn = 1.f / (1.f + expf(x));   // = 1 - sigmoid(x)
                nsum += -logf(sn + 1e-8f);
            }
        }
    }
    #pragma unroll
    for (int m = 1; m < 64; m <<= 1) nsum += __shfl_xor(nsum, m, 64);
    if ((t & 63) == 0) red2[t >> 6] = nsum;
    __syncthreads();
    if (t == 0) atomicAdd(&acc[32], red2[0] + red2[1] + red2[2] + red2[3]);
}

// ---------------- CPC pos loss: b-diagonal dots, sliding 3-row window ----------------
// pos_logit[b,l,k] = ctx[b,l].feat[b,l+k]. Grid (32 b, 4 quarter) x 256 thr;
// wave wv handles 32 consecutive l's. Lane owns d = j*64+lane (coalesced).
__global__ __launch_bounds__(256) void cp_pos(
    const float* __restrict__ feat, const float* __restrict__ ctx,
    float* __restrict__ acc)
{
    int b    = blockIdx.x;
    int q4   = blockIdx.y;
    int wv   = threadIdx.x >> 6;
    int lane = threadIdx.x & 63;
    int l0   = q4 * 128 + wv * 32;
    const float* cb_ = ctx + (long)b * NT * ND;
    const float* fb_ = feat + (long)b * NT * ND;

    float F1[16], F2[16], F3[16];
    #pragma unroll
    for (int j = 0; j < 16; ++j) {
        F1[j] = fb_[(long)(l0 + 1) * ND + j * 64 + lane];
        F2[j] = fb_[(long)(l0 + 2) * ND + j * 64 + lane];
        F3[j] = fb_[(long)(l0 + 3) * ND + j * 64 + lane];
    }
    float posacc = 0.f;
    for (int li = 0; li < 32; ++li) {
        int l = l0 + li;
        float p1 = 0.f, p2 = 0.f, p3 = 0.f;
        #pragma unroll
        for (int j = 0; j < 16; ++j) {
            float cv = cb_[(long)l * ND + j * 64 + lane];
            p1 += cv * F1[j]; p2 += cv * F2[j]; p3 += cv * F3[j];
        }
        #pragma unroll
        for (int m = 1; m < 64; m <<= 1) {
            p1 += __shfl_xor(p1, m, 64);
            p2 += __shfl_xor(p2, m, 64);
            p3 += __shfl_xor(p3, m, 64);
        }
        if (l + 1 < NT) posacc += -logf(1.f / (1.f + expf(-p1)) + 1e-8f);
        if (l + 2 < NT) posacc += -logf(1.f / (1.f + expf(-p2)) + 1e-8f);
        if (l + 3 < NT) posacc += -logf(1.f / (1.f + expf(-p3)) + 1e-8f);
        // slide window
        #pragma unroll
        for (int j = 0; j < 16; ++j) { F1[j] = F2[j]; F2[j] = F3[j]; }
        if (l + 4 < NT) {
            #pragma unroll
            for (int j = 0; j < 16; ++j) F3[j] = fb_[(long)(l + 4) * ND + j * 64 + lane];
        }
    }
    if (lane == 0) atomicAdd(&acc[b], posacc);
}

// ---------------- finalize ----------------
__global__ void finalize_kernel(const float* __restrict__ acc, float* __restrict__ out) {
    int b = threadIdx.x;
    if (b < 32) {
        float cp = (acc[b] + 0.25f * acc[32] * (1.0f / 1024.0f)) * (1.0f / 1527.0f);
        float vq = 1.25f * acc[33] * (1.0f / 16777216.0f);
        out[b] = cp + vq;
    }
}

// ---------------- launch ----------------
extern "C" void kernel_launch(void* const* d_in, const int* in_sizes, int n_in,
                              void* d_out, int out_size, void* d_ws, size_t ws_size,
                              hipStream_t stream)
{
    const float* feat   = (const float*)d_in[0];
    const float* cb     = (const float*)d_in[1];
    const float* W_ih   = (const float*)d_in[2];
    const float* W_hh   = (const float*)d_in[3];
    const float* b_ih   = (const float*)d_in[4];
    const float* b_hh   = (const float*)d_in[5];
    const float* W_proj = (const float*)d_in[6];
    const float* b_proj = (const float*)d_in[7];
    const int*   nperm  = (const int*)d_in[8];

    float* outq    = (float*)d_out;
    float* outidx  = outq + 16777216;
    float* outloss = outq + 16793600;

    char* ws = (char*)d_ws;
    float*          ctx  = (float*)(ws);                       //  67,108,864 B
    unsigned short* Whi  = (unsigned short*)(ws + 67108864);   //   6,291,456 B
    unsigned short* Wlo  = (unsigned short*)(ws + 73400320);   //   6,291,456 B
    unsigned short* Phi  = (unsigned short*)(ws + 79691776);   //   2,097,152 B
    unsigned short* Plo  = (unsigned short*)(ws + 81788928);   //   2,097,152 B
    float*          GIcb = (float*)(ws + 83886080);            //   3,145,728 B
    int*            idxi = (int*)(ws + 87031808);              //      65,536 B
    float*          acc  = (float*)(ws + 87097344);            //  256 B acc
    int*            slots= (int*)(ws + 87097600);              //  1024 B barrier slots
    unsigned short* hA   = (unsigned short*)(ws + 87098624);   //  262,144 B h frag bufs
    unsigned short* cbHi = (unsigned short*)(ws + 87360768);   //     524,288 B
    unsigned short* cbLo = (unsigned short*)(ws + 87885056);   //     524,288 B
    float*          ccg  = (float*)(ws + 88409344);            //       1,024 B

    // zero acc (256) + slots (1024) + hA buffer 0 hi+lo both groups (131072)
    hipMemsetAsync(acc, 0, 256 + 1024 + 131072, stream);
    prep_w<<<12288, 256, 0, stream>>>(W_hh, Whi, Wlo);
    prep_w<<<4096, 256, 0, stream>>>(W_proj, Phi, Plo);
    prep_split<<<128, 256, 0, stream>>>(cb, cbHi, cbLo);
    cc_kernel<<<1, 256, 0, stream>>>(cb, ccg);
    quantize_mfma<<<256, 256, 0, stream>>>(feat, cb, cbHi, cbLo, ccg,
                                           outq, outidx, idxi, acc);
    // GIcb = codebook @ W_ih^T + b_ih  (256x3072, K=1024)
    gemm_nt<<<dim3(24, 2), 256, 0, stream>>>(cb, W_ih, b_ih, GIcb, NG, ND);
    // persistent GRU: 513 in-kernel steps, ctx fused (tile1 cols 8-15 = W_proj)
    gru_persist<<<GRU_BLOCKS, 256, 0, stream>>>(ctx, Whi, Wlo, Phi, Plo, GIcb, idxi,
                                                b_hh, b_proj, hA, slots);
    cp_s<<<511, 256, 0, stream>>>(feat, ctx, nperm, acc);
    cp_pos<<<dim3(32, 4), 256, 0, stream>>>(feat, ctx, acc);
    finalize_kernel<<<1, 64, 0, stream>>>(acc, outloss);
}

// Round 6
// 2197.688 us; speedup vs baseline: 2.8994x; 1.0341x over previous
//
#include <hip/hip_runtime.h>
#include <stdint.h>

// Problem constants (fixed by reference): B=32, T=512, d=1024, Kcb=256
#define NB    32
#define NT    512
#define ND    1024
#define NG    3072      // 3*d
#define NROW  16384     // B*T
#define KCB   256
#define GRU_BLOCKS 256  // 2 independent batch-groups x 128 col-blocks

typedef float  f32x4 __attribute__((ext_vector_type(4)));
typedef short  s16x8 __attribute__((ext_vector_type(8)));
typedef int    i32x4 __attribute__((ext_vector_type(4)));

// ---------------- bf16 helpers (hi/lo split precision) ----------------
__device__ __forceinline__ unsigned short f32_to_bf16(float x) {
    union { float f; unsigned int u; } v; v.f = x;
    unsigned int u = v.u;
    return (unsigned short)((u + 0x7FFFu + ((u >> 16) & 1u)) >> 16);
}
__device__ __forceinline__ float bf16_to_f32(unsigned short h) {
    union { float f; unsigned int u; } v; v.u = ((unsigned int)h) << 16; return v.f;
}

// LLC-coherent (L1/L2-bypassing) accesses — cross-XCD fresh without fences.
__device__ __forceinline__ i32x4 llc_load16i(const int* p) {
    i32x4 r;
    asm volatile("global_load_dwordx4 %0, %1, off sc0 sc1" : "=v"(r) : "v"(p) : "memory");
    return r;
}
__device__ __forceinline__ void llc_store4(int* p, int v) {
    asm volatile("global_store_dword %0, %1, off sc0 sc1" :: "v"(p), "v"(v) : "memory");
}

// ---------------- fused prep: hi/lo splits of W_hh, W_proj, cb + ||c||^2 ----------------
__device__ __forceinline__ void split8(const float* __restrict__ X,
                                       unsigned short* __restrict__ Hi,
                                       unsigned short* __restrict__ Lo, int blk) {
    long i8 = ((long)blk * 256 + threadIdx.x) * 8;
    float4 a = *(const float4*)(X + i8);
    float4 b = *(const float4*)(X + i8 + 4);
    float xs[8] = {a.x, a.y, a.z, a.w, b.x, b.y, b.z, b.w};
    s16x8 hi, lo;
    #pragma unroll
    for (int j = 0; j < 8; ++j) {
        unsigned short h = f32_to_bf16(xs[j]);
        hi[j] = (short)h;
        lo[j] = (short)f32_to_bf16(xs[j] - bf16_to_f32(h));
    }
    *(s16x8*)(Hi + i8) = hi;
    *(s16x8*)(Lo + i8) = lo;
}

__global__ __launch_bounds__(256) void prep_fused(
    const float* __restrict__ Whh, const float* __restrict__ Wproj,
    const float* __restrict__ cb,
    unsigned short* __restrict__ Whi, unsigned short* __restrict__ Wlo,
    unsigned short* __restrict__ Phi, unsigned short* __restrict__ Plo,
    unsigned short* __restrict__ cbHi, unsigned short* __restrict__ cbLo,
    float* __restrict__ ccg)
{
    int bid = blockIdx.x;
    if (bid < 1536)      split8(Whh,   Whi,  Wlo,  bid);          // 3072x1024
    else if (bid < 2048) split8(Wproj, Phi,  Plo,  bid - 1536);   // 1024x1024
    else if (bid < 2176) split8(cb,    cbHi, cbLo, bid - 2048);   // 256x1024
    else {
        // ||c||^2 in fp64, one block
        int c = threadIdx.x;
        const float4* row = (const float4*)(cb + (long)c * ND);
        double s = 0.0;
        for (int i = 0; i < 256; ++i) {
            float4 v = row[i];
            s += (double)v.x * (double)v.x + (double)v.y * (double)v.y
               + (double)v.z * (double)v.z + (double)v.w * (double)v.w;
        }
        ccg[c] = (float)s;
    }
}

// ---------------- MFMA quantize: in-register feat hi/lo split ----------------
__global__ __launch_bounds__(256, 1) void quantize_mfma(
    const float* __restrict__ feat, const float* __restrict__ cb,
    const unsigned short* __restrict__ cHi, const unsigned short* __restrict__ cLo,
    const float* __restrict__ ccg,
    float* __restrict__ out_q, float* __restrict__ out_idx,
    int* __restrict__ idxi, float* __restrict__ acc)
{
    __shared__ unsigned short cbsH[256][64];   // 32 KB, k XOR-swizzled
    __shared__ unsigned short cbsL[256][64];   // 32 KB
    __shared__ float ccs[256];
    __shared__ int   widx[64];
    __shared__ float sp[4];

    int tid  = threadIdx.x;
    int lane = tid & 63;
    int w    = tid >> 6;
    int r0   = blockIdx.x * 64;
    int tm   = lane & 15;
    int q    = lane >> 4;

    ccs[tid] = ccg[tid];

    f32x4 dacc[16];
    #pragma unroll
    for (int n = 0; n < 16; ++n) dacc[n] = (f32x4){0.f, 0.f, 0.f, 0.f};

    const long arow = (long)(r0 + w * 16 + tm) * ND;

    for (int kc = 0; kc < 16; ++kc) {
        int k0 = kc * 64;
        #pragma unroll
        for (int it = 0; it < 8; ++it) {
            int u    = it * 256 + tid;
            int code = u >> 3;
            int j8   = u & 7;
            int ksw  = (j8 * 8) ^ ((code & 7) << 3);
            *(s16x8*)&cbsH[code][ksw] = *(const s16x8*)(cHi + (long)code * ND + k0 + j8 * 8);
            *(s16x8*)&cbsL[code][ksw] = *(const s16x8*)(cLo + (long)code * ND + k0 + j8 * 8);
        }
        float4 a0 = *(const float4*)(feat + arow + k0 + q * 8);
        float4 a1 = *(const float4*)(feat + arow + k0 + q * 8 + 4);
        float4 a2 = *(const float4*)(feat + arow + k0 + 32 + q * 8);
        float4 a3 = *(const float4*)(feat + arow + k0 + 32 + q * 8 + 4);
        s16x8 ah0, al0, ah1, al1;
        {
            float xs[8] = {a0.x, a0.y, a0.z, a0.w, a1.x, a1.y, a1.z, a1.w};
            #pragma unroll
            for (int j = 0; j < 8; ++j) {
                unsigned short h = f32_to_bf16(xs[j]);
                ah0[j] = (short)h;
                al0[j] = (short)f32_to_bf16(xs[j] - bf16_to_f32(h));
            }
            float ys[8] = {a2.x, a2.y, a2.z, a2.w, a3.x, a3.y, a3.z, a3.w};
            #pragma unroll
            for (int j = 0; j < 8; ++j) {
                unsigned short h = f32_to_bf16(ys[j]);
                ah1[j] = (short)h;
                al1[j] = (short)f32_to_bf16(ys[j] - bf16_to_f32(h));
            }
        }
        __syncthreads();
        int ksw0 = (q * 8) ^ ((tm & 7) << 3);
        int ksw1 = (32 + q * 8) ^ ((tm & 7) << 3);
        #pragma unroll
        for (int n = 0; n < 16; ++n) {
            s16x8 bh0 = *(const s16x8*)&cbsH[n * 16 + tm][ksw0];
            s16x8 bh1 = *(const s16x8*)&cbsH[n * 16 + tm][ksw1];
            s16x8 bl0 = *(const s16x8*)&cbsL[n * 16 + tm][ksw0];
            s16x8 bl1 = *(const s16x8*)&cbsL[n * 16 + tm][ksw1];
            dacc[n] = __builtin_amdgcn_mfma_f32_16x16x32_bf16(ah0, bh0, dacc[n], 0, 0, 0);
            dacc[n] = __builtin_amdgcn_mfma_f32_16x16x32_bf16(al0, bh0, dacc[n], 0, 0, 0);
            dacc[n] = __builtin_amdgcn_mfma_f32_16x16x32_bf16(ah0, bl0, dacc[n], 0, 0, 0);
            dacc[n] = __builtin_amdgcn_mfma_f32_16x16x32_bf16(ah1, bh1, dacc[n], 0, 0, 0);
            dacc[n] = __builtin_amdgcn_mfma_f32_16x16x32_bf16(al1, bh1, dacc[n], 0, 0, 0);
            dacc[n] = __builtin_amdgcn_mfma_f32_16x16x32_bf16(ah1, bl1, dacc[n], 0, 0, 0);
        }
        __syncthreads();
    }

    float best[4] = {3.4e38f, 3.4e38f, 3.4e38f, 3.4e38f};
    int   bidx[4] = {0, 0, 0, 0};
    #pragma unroll
    for (int n = 0; n < 16; ++n) {
        int code = n * 16 + tm;
        float ccv = ccs[code];
        #pragma unroll
        for (int r = 0; r < 4; ++r) {
            float d = ccv - 2.f * dacc[n][r];
            if (d < best[r]) { best[r] = d; bidx[r] = code; }
        }
    }
    #pragma unroll
    for (int r = 0; r < 4; ++r) {
        #pragma unroll
        for (int m = 1; m < 16; m <<= 1) {
            float ob = __shfl_xor(best[r], m, 64);
            int   oi = __shfl_xor(bidx[r], m, 64);
            if (ob < best[r] || (ob == best[r] && oi < bidx[r])) { best[r] = ob; bidx[r] = oi; }
        }
        if (tm == 0) {
            int row  = q * 4 + r;
            int grow = r0 + w * 16 + row;
            widx[w * 16 + row] = bidx[r];
            out_idx[grow] = (float)bidx[r];
            idxi[grow]    = bidx[r];
        }
    }
    __syncthreads();

    float ssd = 0.f;
    for (int r = 0; r < 64; ++r) {
        int win = widx[r];
        float4 qv = ((const float4*)(cb + (long)win * ND))[tid];
        ((float4*)(out_q + (long)(r0 + r) * ND))[tid] = qv;
        float4 fv = ((const float4*)(feat + (long)(r0 + r) * ND))[tid];
        float dx = fv.x - qv.x, dy = fv.y - qv.y, dz = fv.z - qv.z, dw = fv.w - qv.w;
        ssd += dx * dx + dy * dy + dz * dz + dw * dw;
    }
    #pragma unroll
    for (int m = 1; m < 64; m <<= 1) ssd += __shfl_xor(ssd, m, 64);
    if (lane == 0) sp[w] = ssd;
    __syncthreads();
    if (tid == 0) atomicAdd(&acc[33], sp[0] + sp[1] + sp[2] + sp[3]);
}

// ---------------- fp32 tiled GEMM (only GIcb = cb @ W_ih^T) ----------------
__global__ __launch_bounds__(256) void gemm_nt(
    const float* __restrict__ A, const float* __restrict__ W,
    const float* __restrict__ bias, float* __restrict__ C, int N, int K)
{
    __shared__ float As[16][132];
    __shared__ float Bs[16][132];
    int tid = threadIdx.x;
    int m0 = blockIdx.y * 128;
    int n0 = blockIdx.x * 128;
    int tx = tid & 15, ty = tid >> 4;

    float accum[8][8];
    #pragma unroll
    for (int i = 0; i < 8; ++i)
        #pragma unroll
        for (int j = 0; j < 8; ++j) accum[i][j] = 0.f;

    for (int k0 = 0; k0 < K; k0 += 16) {
        #pragma unroll
        for (int i = 0; i < 2; ++i) {
            int f   = tid + i * 256;
            int row = f >> 2;
            int kq  = f & 3;
            float4 a = *(const float4*)(A + (long)(m0 + row) * K + k0 + kq * 4);
            As[kq * 4 + 0][row] = a.x; As[kq * 4 + 1][row] = a.y;
            As[kq * 4 + 2][row] = a.z; As[kq * 4 + 3][row] = a.w;
            float4 b = *(const float4*)(W + (long)(n0 + row) * K + k0 + kq * 4);
            Bs[kq * 4 + 0][row] = b.x; Bs[kq * 4 + 1][row] = b.y;
            Bs[kq * 4 + 2][row] = b.z; Bs[kq * 4 + 3][row] = b.w;
        }
        __syncthreads();
        #pragma unroll
        for (int kk = 0; kk < 16; ++kk) {
            float4 a01 = *(const float4*)&As[kk][ty * 8];
            float4 a23 = *(const float4*)&As[kk][ty * 8 + 4];
            float4 b01 = *(const float4*)&Bs[kk][tx * 8];
            float4 b23 = *(const float4*)&Bs[kk][tx * 8 + 4];
            float av[8] = {a01.x, a01.y, a01.z, a01.w, a23.x, a23.y, a23.z, a23.w};
            float bv[8] = {b01.x, b01.y, b01.z, b01.w, b23.x, b23.y, b23.z, b23.w};
            #pragma unroll
            for (int i = 0; i < 8; ++i)
                #pragma unroll
                for (int j = 0; j < 8; ++j) accum[i][j] += av[i] * bv[j];
        }
        __syncthreads();
    }
    #pragma unroll
    for (int i = 0; i < 8; ++i) {
        float* crow = C + (long)(m0 + ty * 8 + i) * N + n0 + tx * 8;
        const float* brow = bias + n0 + tx * 8;
        float4 o0, o1;
        o0.x = accum[i][0] + brow[0]; o0.y = accum[i][1] + brow[1];
        o0.z = accum[i][2] + brow[2]; o0.w = accum[i][3] + brow[3];
        o1.x = accum[i][4] + brow[4]; o1.y = accum[i][5] + brow[5];
        o1.z = accum[i][6] + brow[6]; o1.w = accum[i][7] + brow[7];
        *(float4*)(crow)     = o0;
        *(float4*)(crow + 4) = o1;
    }
}

// ---------------- persistent GRU v10: epoch-in-data h exchange ----------------
// h element = ONE dword: low16 = int16 fixed-point h (x32767; |h|<1 by GRU
// algebra), high16 = epoch (production step + 1). Consumers validate epochs IN
// the loaded A-fragments and retry on staleness. This deletes the poll RT, the
// producer's vmcnt(0) store drain, and the slot publish from the per-step chain.
// Traffic unchanged (4B/elem, same as the old hi+lo ushort pair). Consumers
// rebuild exact bf16 hi/lo fragments in-register (int16->f32 exact; truncation
// split lossless for <=15-bit ints); MFMA output descaled by 1/32767.
__global__ __launch_bounds__(256, 1) void gru_persist(
    float* ctxp,
    const unsigned short* __restrict__ Whi, const unsigned short* __restrict__ Wlo,
    const unsigned short* __restrict__ Phi, const unsigned short* __restrict__ Plo,
    const float* __restrict__ GIcb, const int* __restrict__ idxi,
    const float* __restrict__ b_hh, const float* __restrict__ b_proj,
    int* hD)              // [2 buf][2 grp][32 kk][64 lane][8] dwords (64KB per buf-grp)
{
    __shared__ unsigned short whi0[32][16][32];   // 32 KB
    __shared__ unsigned short whi1[32][16][32];   // 32 KB
    __shared__ float red[4][64][9];               // 9.2 KB

    int tid  = threadIdx.x;
    int lane = tid & 63;
    int w    = tid >> 6;
    int bid  = blockIdx.x;
    int grp  = bid >> 7;
    int bidp = bid & 127;
    int jb   = bidp * 8;
    int q    = lane >> 4;
    int tc   = lane & 15;

    // ---- stage W-hi slices into LDS (32 virtual rows x 1024) ----
    for (int it = 0; it < 16; ++it) {
        int u8  = it * 256 + tid;
        int r32 = u8 >> 7;
        int k   = (u8 & 127) * 8;
        int g = r32 >> 3, r = r32 & 7;
        const unsigned short* src = (g < 3)
            ? (Whi + (long)((g << 10) + jb + r) * 1024 + k)
            : (Phi + (long)(jb + r) * 1024 + k);
        s16x8 v = *(const s16x8*)src;
        if (g == 0)      *(s16x8*)&whi0[k >> 5][r][k & 31]     = v;
        else if (g == 1) *(s16x8*)&whi0[k >> 5][8 + r][k & 31] = v;
        else if (g == 2) *(s16x8*)&whi1[k >> 5][r][k & 31]     = v;
        else             *(s16x8*)&whi1[k >> 5][8 + r][k & 31] = v;
    }

    // ---- pin W-lo fragments in registers ----
    s16x8 wlof[8][2];
    #pragma unroll
    for (int kl = 0; kl < 8; ++kl) {
        int kg = w * 256 + kl * 32 + q * 8;
        int row0 = (tc < 8) ? (jb + tc) : (1024 + jb + (tc - 8));
        wlof[kl][0] = *(const s16x8*)(Wlo + (long)row0 * 1024 + kg);
        wlof[kl][1] = (tc < 8)
            ? *(const s16x8*)(Wlo + (long)(2048 + jb + tc) * 1024 + kg)
            : *(const s16x8*)(Plo + (long)(jb + (tc - 8)) * 1024 + kg);
    }
    __syncthreads();

    // ---- epilogue constants ----
    int ebg = (tid >> 3) & 15;
    int eb  = grp * 16 + ebg;
    int ejl = tid & 7;
    int jg  = jb + ejl;
    int eq  = ebg >> 2, eer = ebg & 3;
    float bhr = b_hh[jg], bhz = b_hh[ND + jg], bhn = b_hh[2 * ND + jg];
    float bpj = b_proj[jg];
    int akk = jg >> 5, aqp = (jg >> 3) & 3, aj8 = jg & 7;
    int alane = aqp * 16 + ebg;
    int awoff = (akk * 64 + alane) * 8 + aj8;
    float hp = 0.f;
    const float ds = 1.f / 32767.f;

    #pragma unroll 1
    for (int t = 0; t <= NT; ++t) {
        int tcl = (t < NT) ? t : (NT - 1);
        int cidx = idxi[eb * NT + tcl];
        const float* gib = GIcb + (long)cidx * NG;
        float gi0 = gib[jg], gi1 = gib[ND + jg], gi2 = gib[2 * ND + jg];

        const int* rD = hD + ((t & 1) * 2 + grp) * 16384;
        int*       wD = hD + (((t + 1) & 1) * 2 + grp) * 16384;

        // ---- load + epoch-validate A-fragments (retry until fresh) ----
        s16x8 Ah[8], Al[8];
        if (t > 0) {
            i32x4 V[16];
            unsigned tag = ((unsigned)t) << 16;
            for (;;) {
                #pragma unroll
                for (int kl = 0; kl < 8; ++kl) {
                    const int* p = rD + (w * 8 + kl) * 512 + lane * 8;
                    V[kl * 2]     = llc_load16i(p);
                    V[kl * 2 + 1] = llc_load16i(p + 4);
                }
                asm volatile("s_waitcnt vmcnt(0)" ::: "memory");
                unsigned bad = 0;
                #pragma unroll
                for (int i = 0; i < 16; ++i) {
                    bad |= ((unsigned)V[i].x ^ tag) | ((unsigned)V[i].y ^ tag)
                         | ((unsigned)V[i].z ^ tag) | ((unsigned)V[i].w ^ tag);
                }
                if (__all((bad & 0xffff0000u) == 0)) break;
                __builtin_amdgcn_s_sleep(1);
            }
            // int16 -> exact bf16 hi/lo fragments
            #pragma unroll
            for (int kl = 0; kl < 8; ++kl) {
                s16x8 ah, al;
                #pragma unroll
                for (int pp = 0; pp < 2; ++pp) {
                    i32x4 v = V[kl * 2 + pp];
                    #pragma unroll
                    for (int e = 0; e < 4; ++e) {
                        int sv = (int)(short)(v[e] & 0xffff);
                        float f = (float)sv;
                        unsigned u = __float_as_uint(f);
                        float hif = __uint_as_float(u & 0xffff0000u);
                        float rem = f - hif;
                        ah[pp * 4 + e] = (short)(u >> 16);
                        al[pp * 4 + e] = (short)(__float_as_uint(rem) >> 16);
                    }
                }
                Ah[kl] = ah; Al[kl] = al;
            }
        } else {
            #pragma unroll
            for (int kl = 0; kl < 8; ++kl) {
                #pragma unroll
                for (int j = 0; j < 8; ++j) { Ah[kl][j] = 0; Al[kl][j] = 0; }
            }
        }

        f32x4 acc0 = (f32x4){0.f, 0.f, 0.f, 0.f};
        f32x4 acc1 = (f32x4){0.f, 0.f, 0.f, 0.f};

        #pragma unroll
        for (int kl = 0; kl < 8; ++kl) {
            int kk = w * 8 + kl;
            s16x8 bh0 = *(const s16x8*)&whi0[kk][tc][q * 8];
            s16x8 bh1 = *(const s16x8*)&whi1[kk][tc][q * 8];
            acc0 = __builtin_amdgcn_mfma_f32_16x16x32_bf16(Ah[kl], bh0, acc0, 0, 0, 0);
            acc1 = __builtin_amdgcn_mfma_f32_16x16x32_bf16(Ah[kl], bh1, acc1, 0, 0, 0);
            acc0 = __builtin_amdgcn_mfma_f32_16x16x32_bf16(Al[kl], bh0, acc0, 0, 0, 0);
            acc1 = __builtin_amdgcn_mfma_f32_16x16x32_bf16(Al[kl], bh1, acc1, 0, 0, 0);
            acc0 = __builtin_amdgcn_mfma_f32_16x16x32_bf16(Ah[kl], wlof[kl][0], acc0, 0, 0, 0);
            acc1 = __builtin_amdgcn_mfma_f32_16x16x32_bf16(Ah[kl], wlof[kl][1], acc1, 0, 0, 0);
        }

        #pragma unroll
        for (int r = 0; r < 4; ++r) {
            red[w][lane][r]     = acc0[r];
            red[w][lane][4 + r] = acc1[r];
        }
        __syncthreads();

        float g0 = 0.f, g1 = 0.f, g2 = 0.f, cx = 0.f;
        #pragma unroll
        for (int ww = 0; ww < 4; ++ww) {
            g0 += red[ww][eq * 16 + ejl][eer];
            g1 += red[ww][eq * 16 + 8 + ejl][eer];
            g2 += red[ww][eq * 16 + ejl][4 + eer];
            cx += red[ww][eq * 16 + 8 + ejl][4 + eer];
        }
        if (tid < 128) {
            if (t < NT) {
                float xr = gi0 + g0 * ds + bhr;
                float xz = gi1 + g1 * ds + bhz;
                float rg = 1.f / (1.f + __expf(-xr));
                float zg = 1.f / (1.f + __expf(-xz));
                float narg = gi2 + rg * (g2 * ds + bhn);
                float e2 = __expf(2.f * narg);
                float ng = 1.f - 2.f / (e2 + 1.f);
                float hnew = (1.f - zg) * ng + zg * hp;
                hp = hnew;
                int hv = (int)rintf(hnew * 32767.f);
                unsigned word = ((unsigned)hv & 0xffffu)
                              | (((unsigned)(t + 1) & 0xffffu) << 16);
                llc_store4(wD + awoff, (int)word);     // fire-and-forget: data IS the flag
            }
            if (t > 0) {
                // ctx row t-1 (A-frags this step were h(t-1)); no consumer until cp.
                ctxp[((long)eb * NT + (t - 1)) * ND + jg] = cx * ds + bpj;
            }
        }
        __syncthreads();   // red[] reuse safety (wave 2/3 sprint guard)
    }
}

// ---------------- fused CPC loss: blocks 0..510 = S-matrix negs, 511.. = pos ----------------
__global__ __launch_bounds__(256) void cp_fused(
    const float* __restrict__ feat, const float* __restrict__ ctx,
    const int* __restrict__ perm, float* __restrict__ acc)
{
    __shared__ float S[32][33];
    __shared__ float red2[4];

    int bid = blockIdx.x;
    int t = threadIdx.x;

    if (bid < 511) {
        int l = bid;
        int b = t >> 3;
        int n0 = (t & 7) * 4;

        const float4* crow = (const float4*)(ctx + ((long)b * NT + l) * ND);
        const float4* f0 = (const float4*)(feat + ((long)(n0 + 0) * NT + l) * ND);
        const float4* f1 = (const float4*)(feat + ((long)(n0 + 1) * NT + l) * ND);
        const float4* f2 = (const float4*)(feat + ((long)(n0 + 2) * NT + l) * ND);
        const float4* f3 = (const float4*)(feat + ((long)(n0 + 3) * NT + l) * ND);
        float s0 = 0.f, s1 = 0.f, s2 = 0.f, s3 = 0.f;
        for (int j = 0; j < 256; ++j) {
            float4 cv = crow[j];
            float4 v0 = f0[j]; s0 += cv.x * v0.x + cv.y * v0.y + cv.z * v0.z + cv.w * v0.w;
            float4 v1 = f1[j]; s1 += cv.x * v1.x + cv.y * v1.y + cv.z * v1.z + cv.w * v1.w;
            float4 v2 = f2[j]; s2 += cv.x * v2.x + cv.y * v2.y + cv.z * v2.z + cv.w * v2.w;
            float4 v3 = f3[j]; s3 += cv.x * v3.x + cv.y * v3.y + cv.z * v3.z + cv.w * v3.w;
        }
        S[b][n0] = s0; S[b][n0 + 1] = s1; S[b][n0 + 2] = s2; S[b][n0 + 3] = s3;
        __syncthreads();

        float nsum = 0.f;
        #pragma unroll
        for (int k = 0; k < 3; ++k) {
            if (l < 511 - k) {
                #pragma unroll
                for (int i = 0; i < 4; ++i) {
                    int idx = t + i * 256;
                    int b2 = idx >> 5, n = idx & 31;
                    int p = perm[k * 32 + n];
                    float x = S[b2][p];
                    float sn = 1.f / (1.f + expf(x));
                    nsum += -logf(sn + 1e-8f);
                }
            }
        }
        #pragma unroll
        for (int m = 1; m < 64; m <<= 1) nsum += __shfl_xor(nsum, m, 64);
        if ((t & 63) == 0) red2[t >> 6] = nsum;
        __syncthreads();
        if (t == 0) atomicAdd(&acc[32], red2[0] + red2[1] + red2[2] + red2[3]);
    } else {
        int r = bid - 511;
        int b    = r >> 2;
        int q4   = r & 3;
        int wv   = t >> 6;
        int lane = t & 63;
        int l0   = q4 * 128 + wv * 32;
        const float* cb_ = ctx + (long)b * NT * ND;
        const float* fb_ = feat + (long)b * NT * ND;

        float F1[16], F2[16], F3[16];
        #pragma unroll
        for (int j = 0; j < 16; ++j) {
            F1[j] = fb_[(long)(l0 + 1) * ND + j * 64 + lane];
            F2[j] = fb_[(long)(l0 + 2) * ND + j * 64 + lane];
            F3[j] = fb_[(long)(l0 + 3) * ND + j * 64 + lane];
        }
        float posacc = 0.f;
        for (int li = 0; li < 32; ++li) {
            int l = l0 + li;
            float p1 = 0.f, p2 = 0.f, p3 = 0.f;
            #pragma unroll
            for (int j = 0; j < 16; ++j) {
                float cv = cb_[(long)l * ND + j * 64 + lane];
                p1 += cv * F1[j]; p2 += cv * F2[j]; p3 += cv * F3[j];
            }
            #pragma unroll
            for (int m = 1; m < 64; m <<= 1) {
                p1 += __shfl_xor(p1, m, 64);
                p2 += __shfl_xor(p2, m, 64);
                p3 += __shfl_xor(p3, m, 64);
            }
            if (l + 1 < NT) posacc += -logf(1.f / (1.f + expf(-p1)) + 1e-8f);
            if (l + 2 < NT) posacc += -logf(1.f / (1.f + expf(-p2)) + 1e-8f);
            if (l + 3 < NT) posacc += -logf(1.f / (1.f + expf(-p3)) + 1e-8f);
            #pragma unroll
            for (int j = 0; j < 16; ++j) { F1[j] = F2[j]; F2[j] = F3[j]; }
            if (l + 4 < NT) {
                #pragma unroll
                for (int j = 0; j < 16; ++j) F3[j] = fb_[(long)(l + 4) * ND + j * 64 + lane];
            }
        }
        if (lane == 0) atomicAdd(&acc[b], posacc);
    }
}

// ---------------- finalize ----------------
__global__ void finalize_kernel(const float* __restrict__ acc, float* __restrict__ out) {
    int b = threadIdx.x;
    if (b < 32) {
        float cp = (acc[b] + 0.25f * acc[32] * (1.0f / 1024.0f)) * (1.0f / 1527.0f);
        float vq = 1.25f * acc[33] * (1.0f / 16777216.0f);
        out[b] = cp + vq;
    }
}

// ---------------- launch ----------------
extern "C" void kernel_launch(void* const* d_in, const int* in_sizes, int n_in,
                              void* d_out, int out_size, void* d_ws, size_t ws_size,
                              hipStream_t stream)
{
    const float* feat   = (const float*)d_in[0];
    const float* cb     = (const float*)d_in[1];
    const float* W_ih   = (const float*)d_in[2];
    const float* W_hh   = (const float*)d_in[3];
    const float* b_ih   = (const float*)d_in[4];
    const float* b_hh   = (const float*)d_in[5];
    const float* W_proj = (const float*)d_in[6];
    const float* b_proj = (const float*)d_in[7];
    const int*   nperm  = (const int*)d_in[8];

    float* outq    = (float*)d_out;
    float* outidx  = outq + 16777216;
    float* outloss = outq + 16793600;

    char* ws = (char*)d_ws;
    float*          ctx  = (float*)(ws);                       //  67,108,864 B
    unsigned short* Whi  = (unsigned short*)(ws + 67108864);   //   6,291,456 B
    unsigned short* Wlo  = (unsigned short*)(ws + 73400320);   //   6,291,456 B
    unsigned short* Phi  = (unsigned short*)(ws + 79691776);   //   2,097,152 B
    unsigned short* Plo  = (unsigned short*)(ws + 81788928);   //   2,097,152 B
    float*          GIcb = (float*)(ws + 83886080);            //   3,145,728 B
    int*            idxi = (int*)(ws + 87031808);              //      65,536 B
    float*          acc  = (float*)(ws + 87097344);            //  256 B
    int*            hD   = (int*)(ws + 87097600);              //  262,144 B h dword bufs
    unsigned short* cbHi = (unsigned short*)(ws + 87359744);   //  524,288 B
    unsigned short* cbLo = (unsigned short*)(ws + 87884032);   //  524,288 B
    float*          ccg  = (float*)(ws + 88408320);            //    1,024 B

    // zero acc (256) + hD both buffers (262144): epochs must start != any step tag
    hipMemsetAsync(acc, 0, 256 + 262144, stream);
    // fused prep: W_hh/W_proj/cb hi-lo splits + ||c||^2   (2177 blocks)
    prep_fused<<<2177, 256, 0, stream>>>(W_hh, W_proj, cb, Whi, Wlo, Phi, Plo,
                                         cbHi, cbLo, ccg);
    quantize_mfma<<<256, 256, 0, stream>>>(feat, cb, cbHi, cbLo, ccg,
                                           outq, outidx, idxi, acc);
    // GIcb = codebook @ W_ih^T + b_ih  (256x3072, K=1024)
    gemm_nt<<<dim3(24, 2), 256, 0, stream>>>(cb, W_ih, b_ih, GIcb, NG, ND);
    // persistent GRU: 513 in-kernel steps, ctx fused, epoch-in-data h exchange
    gru_persist<<<GRU_BLOCKS, 256, 0, stream>>>(ctx, Whi, Wlo, Phi, Plo, GIcb, idxi,
                                                b_hh, b_proj, hD);
    // fused CPC loss: 511 S-blocks + 128 pos-blocks
    cp_fused<<<639, 256, 0, stream>>>(feat, ctx, nperm, acc);
    finalize_kernel<<<1, 64, 0, stream>>>(acc, outloss);
}